// Round 1
// baseline (1576.667 us; speedup 1.0000x reference)
//
#include <hip/hip_runtime.h>

#define N_NODES 100000
#define N_EDGES 1600000
#define DIM 128

// ---------------- CSR build ----------------

__global__ void k_zero(int* __restrict__ p, int n) {
  int i = blockIdx.x * blockDim.x + threadIdx.x;
  if (i < n) p[i] = 0;
}

__global__ void k_count(const int* __restrict__ dst, int* __restrict__ cnt) {
  int i = blockIdx.x * blockDim.x + threadIdx.x;
  if (i < N_EDGES) atomicAdd(&cnt[dst[i]], 1);
}

// 1024-thread block inclusive scan; offs[gid+1] = local inclusive, partials[b] = block sum
__global__ void k_scan_blk(const int* __restrict__ cnt, int* __restrict__ offs,
                           int* __restrict__ partials) {
  int tid = threadIdx.x;
  int gid = blockIdx.x * 1024 + tid;
  int v = (gid < N_NODES) ? cnt[gid] : 0;
  int lane = tid & 63, w = tid >> 6;
  int s = v;
#pragma unroll
  for (int d = 1; d < 64; d <<= 1) {
    int t = __shfl_up(s, d);
    if (lane >= d) s += t;
  }
  __shared__ int wsum[16];
  if (lane == 63) wsum[w] = s;
  __syncthreads();
  if (tid < 16) {
    int t2 = wsum[tid];
#pragma unroll
    for (int d = 1; d < 16; d <<= 1) {
      int u = __shfl_up(t2, d);
      if (tid >= d) t2 += u;
    }
    wsum[tid] = t2;
  }
  __syncthreads();
  if (w > 0) s += wsum[w - 1];
  if (gid < N_NODES) offs[gid + 1] = s;
  if (tid == 1023) partials[blockIdx.x] = s;
}

__global__ void k_scan_part(int* __restrict__ partials, int nb) {
  __shared__ int tmp[128];
  int tid = threadIdx.x;
  tmp[tid] = (tid < nb) ? partials[tid] : 0;
  __syncthreads();
  for (int d = 1; d < 128; d <<= 1) {
    int t = (tid >= d) ? tmp[tid - d] : 0;
    __syncthreads();
    tmp[tid] += t;
    __syncthreads();
  }
  if (tid < nb) partials[tid] = (tid > 0) ? tmp[tid - 1] : 0;  // exclusive
}

__global__ void k_scan_add(int* __restrict__ offs, const int* __restrict__ partials) {
  int i = blockIdx.x * blockDim.x + threadIdx.x;
  if (i == 0) offs[0] = 0;
  if (i < N_NODES) offs[i + 1] += partials[i >> 10];
}

__global__ void k_prep(const int* __restrict__ offs, const int* __restrict__ cnt,
                       int* __restrict__ cursor, float* __restrict__ deg_inv) {
  int i = blockIdx.x * blockDim.x + threadIdx.x;
  if (i < N_NODES) {
    cursor[i] = offs[i];
    deg_inv[i] = 1.0f / (float)max(cnt[i], 1);
  }
}

__global__ void k_fill(const int* __restrict__ src, const int* __restrict__ dst,
                       int* __restrict__ cursor, int* __restrict__ esrc) {
  int i = blockIdx.x * blockDim.x + threadIdx.x;
  if (i < N_EDGES) {
    int p = atomicAdd(&cursor[dst[i]], 1);
    esrc[p] = src[i];
  }
}

// ---------------- aggregation: one wave per destination node ----------------

__global__ void k_agg(const float* __restrict__ h, const int* __restrict__ offs,
                      const int* __restrict__ esrc, const float* __restrict__ deg_inv,
                      float* __restrict__ mean) {
  int wid = (blockIdx.x * blockDim.x + threadIdx.x) >> 6;  // node id
  int lane = threadIdx.x & 63;
  if (wid >= N_NODES) return;
  int beg = offs[wid], end = offs[wid + 1];
  float2 a0 = {0.f, 0.f}, a1 = {0.f, 0.f};
  int e = beg;
  for (; e + 1 < end; e += 2) {
    int s0 = esrc[e];
    int s1 = esrc[e + 1];
    float2 v0 = *reinterpret_cast<const float2*>(&h[s0 * DIM + lane * 2]);
    float2 v1 = *reinterpret_cast<const float2*>(&h[s1 * DIM + lane * 2]);
    a0.x += v0.x; a0.y += v0.y;
    a1.x += v1.x; a1.y += v1.y;
  }
  if (e < end) {
    int s0 = esrc[e];
    float2 v0 = *reinterpret_cast<const float2*>(&h[s0 * DIM + lane * 2]);
    a0.x += v0.x; a0.y += v0.y;
  }
  float di = deg_inv[wid];
  float2 r = {(a0.x + a1.x) * di, (a0.y + a1.y) * di};
  *reinterpret_cast<float2*>(&mean[wid * DIM + lane * 2]) = r;
}

// ---------------- fused dual-GEMM: out = act(h@ws + mean@wn + b) ----------------
// 64 rows x 128 cols per block, 256 threads, 4x8 outputs/thread, K chunked by 32.

template <int RELU>
__global__ __launch_bounds__(256) void k_gemm(
    const float* __restrict__ h, const float* __restrict__ mean,
    const float* __restrict__ ws, const float* __restrict__ wn,
    const float* __restrict__ bias, float* __restrict__ out) {
  __shared__ float sWs[32][128];
  __shared__ float sWn[32][128];
  __shared__ float sHT[32][64];
  __shared__ float sMT[32][64];

  const int t = threadIdx.x;
  const int rg = t >> 4;   // 0..15 -> rows 4*rg..4*rg+3
  const int cg = t & 15;   // 0..15 -> cols 8*cg..8*cg+7
  const int r0 = blockIdx.x * 64;

  float acc[4][8];
#pragma unroll
  for (int i = 0; i < 4; ++i)
#pragma unroll
    for (int j = 0; j < 8; ++j) acc[i][j] = 0.f;

  for (int kk = 0; kk < DIM; kk += 32) {
    __syncthreads();
    // stage weights (32x128 each)
    {
      const float4* gws = reinterpret_cast<const float4*>(ws + kk * DIM);
      const float4* gwn = reinterpret_cast<const float4*>(wn + kk * DIM);
      float4* lws = reinterpret_cast<float4*>(&sWs[0][0]);
      float4* lwn = reinterpret_cast<float4*>(&sWn[0][0]);
#pragma unroll
      for (int i = 0; i < 4; ++i) {
        lws[t + i * 256] = gws[t + i * 256];
        lwn[t + i * 256] = gwn[t + i * 256];
      }
    }
    // stage transposed h / mean tiles (64 rows x 32 k)
#pragma unroll
    for (int i = 0; i < 2; ++i) {
      int fid = t + i * 256;  // 0..511
      int r = fid >> 3;
      int q = fid & 7;
      int row = r0 + r;
      float4 hv = {0.f, 0.f, 0.f, 0.f}, mv = {0.f, 0.f, 0.f, 0.f};
      if (row < N_NODES) {
        hv = *reinterpret_cast<const float4*>(&h[row * DIM + kk + q * 4]);
        mv = *reinterpret_cast<const float4*>(&mean[row * DIM + kk + q * 4]);
      }
      sHT[q * 4 + 0][r] = hv.x; sHT[q * 4 + 1][r] = hv.y;
      sHT[q * 4 + 2][r] = hv.z; sHT[q * 4 + 3][r] = hv.w;
      sMT[q * 4 + 0][r] = mv.x; sMT[q * 4 + 1][r] = mv.y;
      sMT[q * 4 + 2][r] = mv.z; sMT[q * 4 + 3][r] = mv.w;
    }
    __syncthreads();
#pragma unroll
    for (int k = 0; k < 32; ++k) {
      float4 a = *reinterpret_cast<const float4*>(&sHT[k][rg * 4]);
      float4 m = *reinterpret_cast<const float4*>(&sMT[k][rg * 4]);
      float4 w0 = *reinterpret_cast<const float4*>(&sWs[k][cg * 8]);
      float4 w1 = *reinterpret_cast<const float4*>(&sWs[k][cg * 8 + 4]);
      float4 u0 = *reinterpret_cast<const float4*>(&sWn[k][cg * 8]);
      float4 u1 = *reinterpret_cast<const float4*>(&sWn[k][cg * 8 + 4]);
      const float av[4] = {a.x, a.y, a.z, a.w};
      const float mv2[4] = {m.x, m.y, m.z, m.w};
      const float wv[8] = {w0.x, w0.y, w0.z, w0.w, w1.x, w1.y, w1.z, w1.w};
      const float uv[8] = {u0.x, u0.y, u0.z, u0.w, u1.x, u1.y, u1.z, u1.w};
#pragma unroll
      for (int i = 0; i < 4; ++i)
#pragma unroll
        for (int j = 0; j < 8; ++j)
          acc[i][j] += av[i] * wv[j] + mv2[i] * uv[j];
    }
  }

  float bv[8];
#pragma unroll
  for (int j = 0; j < 8; ++j) bv[j] = bias[cg * 8 + j];
#pragma unroll
  for (int i = 0; i < 4; ++i) {
    int row = r0 + rg * 4 + i;
    if (row < N_NODES) {
      float o[8];
#pragma unroll
      for (int j = 0; j < 8; ++j) {
        float v = acc[i][j] + bv[j];
        if (RELU) v = fmaxf(v, 0.f);
        o[j] = v;
      }
      float4* po = reinterpret_cast<float4*>(&out[row * DIM + cg * 8]);
      po[0] = make_float4(o[0], o[1], o[2], o[3]);
      po[1] = make_float4(o[4], o[5], o[6], o[7]);
    }
  }
}

// ---------------- driver ----------------

extern "C" void kernel_launch(void* const* d_in, const int* in_sizes, int n_in,
                              void* d_out, int out_size, void* d_ws, size_t ws_size,
                              hipStream_t stream) {
  const float* x = (const float*)d_in[0];
  const int* src = (const int*)d_in[1];
  const int* dst = (const int*)d_in[2];
  const float* Ws[4];
  const float* Wn[4];
  const float* Bi[4];
  for (int i = 0; i < 4; ++i) {
    Ws[i] = (const float*)d_in[3 + 3 * i];
    Wn[i] = (const float*)d_in[4 + 3 * i];
    Bi[i] = (const float*)d_in[5 + 3 * i];
  }
  float* out = (float*)d_out;

  char* p = (char*)d_ws;
  auto take = [&](size_t bytes) {
    void* r = (void*)p;
    p += (bytes + 255) & ~(size_t)255;
    return r;
  };
  int* cnt = (int*)take((size_t)N_NODES * 4);
  int* offs = (int*)take((size_t)(N_NODES + 1) * 4);
  int* cursor = (int*)take((size_t)N_NODES * 4);
  int* partials = (int*)take(128 * 4);
  float* deg_inv = (float*)take((size_t)N_NODES * 4);
  int* esrc = (int*)take((size_t)N_EDGES * 4);
  float* bufA = (float*)take((size_t)N_NODES * DIM * 4);
  float* bufB = (float*)take((size_t)N_NODES * DIM * 4);
  float* bufM = (float*)take((size_t)N_NODES * DIM * 4);

  const int NB = (N_NODES + 1023) / 1024;  // 98

  // CSR build (once; edges are layer-invariant)
  k_zero<<<(N_NODES + 255) / 256, 256, 0, stream>>>(cnt, N_NODES);
  k_count<<<(N_EDGES + 255) / 256, 256, 0, stream>>>(dst, cnt);
  k_scan_blk<<<NB, 1024, 0, stream>>>(cnt, offs, partials);
  k_scan_part<<<1, 128, 0, stream>>>(partials, NB);
  k_scan_add<<<(N_NODES + 255) / 256, 256, 0, stream>>>(offs, partials);
  k_prep<<<(N_NODES + 255) / 256, 256, 0, stream>>>(offs, cnt, cursor, deg_inv);
  k_fill<<<(N_EDGES + 255) / 256, 256, 0, stream>>>(src, dst, cursor, esrc);

  const int AGG_BLOCKS = (N_NODES + 3) / 4;          // 4 waves/block, 1 node/wave
  const int GEMM_BLOCKS = (N_NODES + 63) / 64;       // 64 rows/block

  const float* hcur = x;
  for (int l = 0; l < 4; ++l) {
    k_agg<<<AGG_BLOCKS, 256, 0, stream>>>(hcur, offs, esrc, deg_inv, bufM);
    float* o = (l == 3) ? out : ((l & 1) ? bufB : bufA);
    if (l < 3)
      k_gemm<1><<<GEMM_BLOCKS, 256, 0, stream>>>(hcur, bufM, Ws[l], Wn[l], Bi[l], o);
    else
      k_gemm<0><<<GEMM_BLOCKS, 256, 0, stream>>>(hcur, bufM, Ws[l], Wn[l], Bi[l], o);
    hcur = o;
  }
}

// Round 2
// 897.410 us; speedup vs baseline: 1.7569x; 1.7569x over previous
//
#include <hip/hip_runtime.h>

#define N_NODES 100000
#define N_EDGES 1600000
#define DIM 128

typedef __attribute__((ext_vector_type(8))) short short8;   // 8 bf16 (MFMA A/B frag)
typedef __attribute__((ext_vector_type(4))) float f32x4;    // MFMA C/D frag

// ---- bf16 split-float helpers: word = (hi16 << 16) | lo16, hi/lo rne bf16 ----
__device__ __forceinline__ unsigned f2bfbits(float f) {
  unsigned u = __float_as_uint(f);
  return (u + 0x7FFFu + ((u >> 16) & 1u)) >> 16;
}
__device__ __forceinline__ float bfbits2f(unsigned b) { return __uint_as_float(b << 16); }
__device__ __forceinline__ unsigned packsplit(float v) {
  unsigned hi = f2bfbits(v);
  unsigned lo = f2bfbits(v - bfbits2f(hi));
  return (hi << 16) | lo;
}
__device__ __forceinline__ float unpack_full(unsigned w) {
  return __uint_as_float(w & 0xFFFF0000u) + __uint_as_float(w << 16);
}

// ---------------- CSR build ----------------

__global__ void k_zero(int* __restrict__ p, int n) {
  int i = blockIdx.x * blockDim.x + threadIdx.x;
  if (i < n) p[i] = 0;
}

__global__ void k_count(const int* __restrict__ dst, int* __restrict__ cnt) {
  int i = blockIdx.x * blockDim.x + threadIdx.x;
  if (i < N_EDGES) atomicAdd(&cnt[dst[i]], 1);
}

__global__ void k_scan_blk(const int* __restrict__ cnt, int* __restrict__ offs,
                           int* __restrict__ partials) {
  int tid = threadIdx.x;
  int gid = blockIdx.x * 1024 + tid;
  int v = (gid < N_NODES) ? cnt[gid] : 0;
  int lane = tid & 63, w = tid >> 6;
  int s = v;
#pragma unroll
  for (int d = 1; d < 64; d <<= 1) {
    int t = __shfl_up(s, d);
    if (lane >= d) s += t;
  }
  __shared__ int wsum[16];
  if (lane == 63) wsum[w] = s;
  __syncthreads();
  if (tid < 16) {
    int t2 = wsum[tid];
#pragma unroll
    for (int d = 1; d < 16; d <<= 1) {
      int u = __shfl_up(t2, d);
      if (tid >= d) t2 += u;
    }
    wsum[tid] = t2;
  }
  __syncthreads();
  if (w > 0) s += wsum[w - 1];
  if (gid < N_NODES) offs[gid + 1] = s;
  if (tid == 1023) partials[blockIdx.x] = s;
}

__global__ void k_scan_part(int* __restrict__ partials, int nb) {
  __shared__ int tmp[128];
  int tid = threadIdx.x;
  tmp[tid] = (tid < nb) ? partials[tid] : 0;
  __syncthreads();
  for (int d = 1; d < 128; d <<= 1) {
    int t = (tid >= d) ? tmp[tid - d] : 0;
    __syncthreads();
    tmp[tid] += t;
    __syncthreads();
  }
  if (tid < nb) partials[tid] = (tid > 0) ? tmp[tid - 1] : 0;  // exclusive
}

__global__ void k_scan_add(int* __restrict__ offs, const int* __restrict__ partials) {
  int i = blockIdx.x * blockDim.x + threadIdx.x;
  if (i == 0) offs[0] = 0;
  if (i < N_NODES) offs[i + 1] += partials[i >> 10];
}

__global__ void k_prep(const int* __restrict__ offs, const int* __restrict__ cnt,
                       int* __restrict__ cursor, float* __restrict__ deg_inv) {
  int i = blockIdx.x * blockDim.x + threadIdx.x;
  if (i < N_NODES) {
    cursor[i] = offs[i];
    deg_inv[i] = 1.0f / (float)max(cnt[i], 1);
  }
}

__global__ void k_fill(const int* __restrict__ src, const int* __restrict__ dst,
                       int* __restrict__ cursor, int* __restrict__ esrc) {
  int i = blockIdx.x * blockDim.x + threadIdx.x;
  if (i < N_EDGES) {
    int p = atomicAdd(&cursor[dst[i]], 1);
    esrc[p] = src[i];
  }
}

// ---------------- x (fp32) -> packed split-float ----------------

__global__ void k_xpsf(const float* __restrict__ x, unsigned* __restrict__ o) {
  int i = blockIdx.x * blockDim.x + threadIdx.x;
  if (i < (N_NODES * DIM) / 4) {
    float4 v = reinterpret_cast<const float4*>(x)[i];
    uint4 w;
    w.x = packsplit(v.x);
    w.y = packsplit(v.y);
    w.z = packsplit(v.z);
    w.w = packsplit(v.w);
    reinterpret_cast<uint4*>(o)[i] = w;
  }
}

// ---------------- weight pack: frag-major bf16 hi/lo ----------------
// Per layer: mats {0:ws_hi, 1:ws_lo, 2:wn_hi, 3:wn_lo};
// index within layer: (((mat*4 + t)*8 + f)*64 + lane)*8 + j
// holds B[k = t*32 + (lane>>4)*8 + j][col = f*16 + (lane&15)]

#define WP_LAYER (4 * 4 * 8 * 64 * 8)  // 65536 ushorts
#define WP_MAT (4 * 8 * 64 * 8)        // 16384 ushorts

__global__ void k_wpack(const float* __restrict__ ws0, const float* __restrict__ wn0,
                        const float* __restrict__ ws1, const float* __restrict__ wn1,
                        const float* __restrict__ ws2, const float* __restrict__ wn2,
                        const float* __restrict__ ws3, const float* __restrict__ wn3,
                        unsigned short* __restrict__ wp) {
  int tid = blockIdx.x * 256 + threadIdx.x;  // 0..32767
  int l = tid & 63;
  int f = (tid >> 6) & 7;
  int t = (tid >> 9) & 3;
  int mat = (tid >> 11) & 3;
  int layer = tid >> 13;
  const float* srcs[8] = {ws0, wn0, ws1, wn1, ws2, wn2, ws3, wn3};
  const float* src = srcs[layer * 2 + (mat >> 1)];
  int isLo = mat & 1;
  unsigned short* dst =
      wp + (size_t)layer * WP_LAYER + ((((mat * 4 + t) * 8 + f) * 64 + l) * 8);
  int k0 = t * 32 + (l >> 4) * 8;
  int col = f * 16 + (l & 15);
#pragma unroll
  for (int j = 0; j < 8; ++j) {
    float v = src[(k0 + j) * DIM + col];
    unsigned hi = f2bfbits(v);
    unsigned bits = isLo ? f2bfbits(v - bfbits2f(hi)) : hi;
    dst[j] = (unsigned short)bits;
  }
}

// ---------------- aggregation: one wave per destination node ----------------

__global__ void k_agg_psf(const unsigned* __restrict__ h, const int* __restrict__ offs,
                          const int* __restrict__ esrc, const float* __restrict__ deg_inv,
                          unsigned* __restrict__ m) {
  int wid = (blockIdx.x * blockDim.x + threadIdx.x) >> 6;  // node id
  int lane = threadIdx.x & 63;
  if (wid >= N_NODES) return;
  int beg = offs[wid], end = offs[wid + 1];
  float a0 = 0.f, a1 = 0.f, b0 = 0.f, b1 = 0.f;
  int e = beg;
  for (; e + 1 < end; e += 2) {
    int s0 = esrc[e];
    int s1 = esrc[e + 1];
    uint2 w0 = *reinterpret_cast<const uint2*>(&h[(size_t)s0 * DIM + lane * 2]);
    uint2 w1 = *reinterpret_cast<const uint2*>(&h[(size_t)s1 * DIM + lane * 2]);
    a0 += unpack_full(w0.x);
    a1 += unpack_full(w0.y);
    b0 += unpack_full(w1.x);
    b1 += unpack_full(w1.y);
  }
  if (e < end) {
    int s0 = esrc[e];
    uint2 w0 = *reinterpret_cast<const uint2*>(&h[(size_t)s0 * DIM + lane * 2]);
    a0 += unpack_full(w0.x);
    a1 += unpack_full(w0.y);
  }
  float di = deg_inv[wid];
  uint2 r;
  r.x = packsplit((a0 + b0) * di);
  r.y = packsplit((a1 + b1) * di);
  *reinterpret_cast<uint2*>(&m[(size_t)wid * DIM + lane * 2]) = r;
}

// ---------------- MFMA dual-GEMM with bf16 hi/lo split ----------------
// out = act(h@ws + mean@wn + b); h,mean in split-float psf format.
// Block = 256 threads = 4 waves; wave computes 64 rows x 128 cols.
// Per slab s in {h, mean}: acc += a_hi*w_hi + a_lo*w_hi + a_hi*w_lo.

template <int RELU, int LAST>
__global__ __launch_bounds__(256) void k_gemm_mfma(
    const unsigned* __restrict__ hpsf, const unsigned* __restrict__ mpsf,
    const unsigned short* __restrict__ wp, const float* __restrict__ bias,
    float* __restrict__ outf, unsigned* __restrict__ outpsf) {
  const int lane = threadIdx.x & 63;
  const int wv = threadIdx.x >> 6;
  const int row0 = blockIdx.x * 256 + wv * 64;
  const int lr = lane & 15;  // row-in-frag (A) / col-in-frag (B, C)
  const int lg = lane >> 4;  // k-group (A,B) / row-group (C)

  f32x4 acc[4][8];
#pragma unroll
  for (int i = 0; i < 4; ++i)
#pragma unroll
    for (int j = 0; j < 8; ++j) acc[i][j] = (f32x4){0.f, 0.f, 0.f, 0.f};

  for (int s = 0; s < 2; ++s) {
    const unsigned* A = s ? mpsf : hpsf;
    const unsigned short* WH = wp + (s ? 2 : 0) * WP_MAT;
    const unsigned short* WL = WH + WP_MAT;
    for (int t = 0; t < 4; ++t) {
      // load + unpack A frags (4 row-frags of 16 rows each)
      short8 ah[4], al[4];
#pragma unroll
      for (int ri = 0; ri < 4; ++ri) {
        int row = row0 + ri * 16 + lr;
        row = min(row, N_NODES - 1);
        const uint4* p =
            reinterpret_cast<const uint4*>(A + (size_t)row * DIM + t * 32 + lg * 8);
        uint4 w0 = p[0];
        uint4 w1 = p[1];
        unsigned wa[8] = {w0.x, w0.y, w0.z, w0.w, w1.x, w1.y, w1.z, w1.w};
#pragma unroll
        for (int j = 0; j < 8; ++j) {
          ah[ri][j] = (short)(wa[j] >> 16);
          al[ri][j] = (short)(wa[j] & 0xFFFFu);
        }
      }
#pragma unroll
      for (int fh = 0; fh < 2; ++fh) {
        short8 bh[4], bl[4];
#pragma unroll
        for (int q = 0; q < 4; ++q) {
          int f = fh * 4 + q;
          bh[q] = *reinterpret_cast<const short8*>(WH + ((t * 8 + f) * 64 + lane) * 8);
          bl[q] = *reinterpret_cast<const short8*>(WL + ((t * 8 + f) * 64 + lane) * 8);
        }
#pragma unroll
        for (int ri = 0; ri < 4; ++ri)
#pragma unroll
          for (int q = 0; q < 4; ++q) {
            int f = fh * 4 + q;
            acc[ri][f] =
                __builtin_amdgcn_mfma_f32_16x16x32_bf16(ah[ri], bh[q], acc[ri][f], 0, 0, 0);
            acc[ri][f] =
                __builtin_amdgcn_mfma_f32_16x16x32_bf16(al[ri], bh[q], acc[ri][f], 0, 0, 0);
            acc[ri][f] =
                __builtin_amdgcn_mfma_f32_16x16x32_bf16(ah[ri], bl[q], acc[ri][f], 0, 0, 0);
          }
      }
    }
  }

  // epilogue: C/D layout col=lane&15, row=(lane>>4)*4+reg
  float bv[8];
#pragma unroll
  for (int f = 0; f < 8; ++f) bv[f] = bias[f * 16 + lr];
#pragma unroll
  for (int ri = 0; ri < 4; ++ri)
#pragma unroll
    for (int f = 0; f < 8; ++f)
#pragma unroll
      for (int r = 0; r < 4; ++r) {
        int row = row0 + ri * 16 + lg * 4 + r;
        if (row < N_NODES) {
          float v = acc[ri][f][r] + bv[f];
          if (RELU) v = fmaxf(v, 0.f);
          size_t idx = (size_t)row * DIM + f * 16 + lr;
          if (LAST)
            outf[idx] = v;
          else
            outpsf[idx] = packsplit(v);
        }
      }
}

// ---------------- driver ----------------

extern "C" void kernel_launch(void* const* d_in, const int* in_sizes, int n_in,
                              void* d_out, int out_size, void* d_ws, size_t ws_size,
                              hipStream_t stream) {
  const float* x = (const float*)d_in[0];
  const int* src = (const int*)d_in[1];
  const int* dst = (const int*)d_in[2];
  const float* Ws[4];
  const float* Wn[4];
  const float* Bi[4];
  for (int i = 0; i < 4; ++i) {
    Ws[i] = (const float*)d_in[3 + 3 * i];
    Wn[i] = (const float*)d_in[4 + 3 * i];
    Bi[i] = (const float*)d_in[5 + 3 * i];
  }
  float* out = (float*)d_out;

  char* p = (char*)d_ws;
  auto take = [&](size_t bytes) {
    void* r = (void*)p;
    p += (bytes + 255) & ~(size_t)255;
    return r;
  };
  int* cnt = (int*)take((size_t)N_NODES * 4);
  int* offs = (int*)take((size_t)(N_NODES + 1) * 4);
  int* cursor = (int*)take((size_t)N_NODES * 4);
  int* partials = (int*)take(128 * 4);
  float* deg_inv = (float*)take((size_t)N_NODES * 4);
  int* esrc = (int*)take((size_t)N_EDGES * 4);
  unsigned* psfA = (unsigned*)take((size_t)N_NODES * DIM * 4);
  unsigned* psfB = (unsigned*)take((size_t)N_NODES * DIM * 4);
  unsigned* mpsf = (unsigned*)take((size_t)N_NODES * DIM * 4);
  unsigned short* wpk = (unsigned short*)take((size_t)4 * WP_LAYER * 2);

  const int NB = (N_NODES + 1023) / 1024;  // 98

  // CSR build (edges are layer-invariant)
  k_zero<<<(N_NODES + 255) / 256, 256, 0, stream>>>(cnt, N_NODES);
  k_count<<<(N_EDGES + 255) / 256, 256, 0, stream>>>(dst, cnt);
  k_scan_blk<<<NB, 1024, 0, stream>>>(cnt, offs, partials);
  k_scan_part<<<1, 128, 0, stream>>>(partials, NB);
  k_scan_add<<<(N_NODES + 255) / 256, 256, 0, stream>>>(offs, partials);
  k_prep<<<(N_NODES + 255) / 256, 256, 0, stream>>>(offs, cnt, cursor, deg_inv);
  k_fill<<<(N_EDGES + 255) / 256, 256, 0, stream>>>(src, dst, cursor, esrc);

  // input conversion + weight pack
  k_xpsf<<<(N_NODES * DIM / 4 + 255) / 256, 256, 0, stream>>>(x, psfA);
  k_wpack<<<128, 256, 0, stream>>>(Ws[0], Wn[0], Ws[1], Wn[1], Ws[2], Wn[2], Ws[3], Wn[3],
                                   wpk);

  const int AGG_BLOCKS = (N_NODES + 3) / 4;    // 4 waves/block, 1 node/wave
  const int GEMM_BLOCKS = (N_NODES + 255) / 256;  // 256 rows/block (64/wave)

  unsigned* hp = psfA;
  unsigned* np = psfB;
  for (int l = 0; l < 4; ++l) {
    k_agg_psf<<<AGG_BLOCKS, 256, 0, stream>>>(hp, offs, esrc, deg_inv, mpsf);
    const unsigned short* wl = wpk + (size_t)l * WP_LAYER;
    if (l < 3) {
      k_gemm_mfma<1, 0><<<GEMM_BLOCKS, 256, 0, stream>>>(hp, mpsf, wl, Bi[l], nullptr, np);
      unsigned* tmp = hp; hp = np; np = tmp;
    } else {
      k_gemm_mfma<0, 1><<<GEMM_BLOCKS, 256, 0, stream>>>(hp, mpsf, wl, Bi[l], out, nullptr);
    }
  }
}

// Round 3
// 729.060 us; speedup vs baseline: 2.1626x; 1.2309x over previous
//
#include <hip/hip_runtime.h>

#define N_NODES 100000
#define N_EDGES 1600000
#define DIM 128

typedef __attribute__((ext_vector_type(8))) _Float16 f16x8;  // MFMA A/B frag (4 VGPRs)
typedef __attribute__((ext_vector_type(4))) float f32x4;     // MFMA C/D frag

// ---------------- CSR build ----------------

__global__ void k_zero(int* __restrict__ p, int n) {
  int i = blockIdx.x * blockDim.x + threadIdx.x;
  if (i < n) p[i] = 0;
}

__global__ void k_count(const int* __restrict__ dst, int* __restrict__ cnt) {
  int i = blockIdx.x * blockDim.x + threadIdx.x;
  if (i < N_EDGES) atomicAdd(&cnt[dst[i]], 1);
}

__global__ void k_scan_blk(const int* __restrict__ cnt, int* __restrict__ offs,
                           int* __restrict__ partials) {
  int tid = threadIdx.x;
  int gid = blockIdx.x * 1024 + tid;
  int v = (gid < N_NODES) ? cnt[gid] : 0;
  int lane = tid & 63, w = tid >> 6;
  int s = v;
#pragma unroll
  for (int d = 1; d < 64; d <<= 1) {
    int t = __shfl_up(s, d);
    if (lane >= d) s += t;
  }
  __shared__ int wsum[16];
  if (lane == 63) wsum[w] = s;
  __syncthreads();
  if (tid < 16) {
    int t2 = wsum[tid];
#pragma unroll
    for (int d = 1; d < 16; d <<= 1) {
      int u = __shfl_up(t2, d);
      if (tid >= d) t2 += u;
    }
    wsum[tid] = t2;
  }
  __syncthreads();
  if (w > 0) s += wsum[w - 1];
  if (gid < N_NODES) offs[gid + 1] = s;
  if (tid == 1023) partials[blockIdx.x] = s;
}

__global__ void k_scan_part(int* __restrict__ partials, int nb) {
  __shared__ int tmp[128];
  int tid = threadIdx.x;
  tmp[tid] = (tid < nb) ? partials[tid] : 0;
  __syncthreads();
  for (int d = 1; d < 128; d <<= 1) {
    int t = (tid >= d) ? tmp[tid - d] : 0;
    __syncthreads();
    tmp[tid] += t;
    __syncthreads();
  }
  if (tid < nb) partials[tid] = (tid > 0) ? tmp[tid - 1] : 0;  // exclusive
}

__global__ void k_scan_add(int* __restrict__ offs, const int* __restrict__ partials) {
  int i = blockIdx.x * blockDim.x + threadIdx.x;
  if (i == 0) offs[0] = 0;
  if (i < N_NODES) offs[i + 1] += partials[i >> 10];
}

__global__ void k_prep(const int* __restrict__ offs, const int* __restrict__ cnt,
                       int* __restrict__ cursor, float* __restrict__ deg_inv) {
  int i = blockIdx.x * blockDim.x + threadIdx.x;
  if (i < N_NODES) {
    cursor[i] = offs[i];
    deg_inv[i] = 1.0f / (float)max(cnt[i], 1);
  }
}

// XCD-partitioned fill: block handles only dst in its partition (blockIdx%8).
// Each partition's esrc slice (~800KB) stays in one XCD's L2 -> writes land once.
#define FILL_BPP 224  // blocks per partition
__global__ void k_fill8(const int* __restrict__ src, const int* __restrict__ dst,
                        int* __restrict__ cursor, int* __restrict__ esrc) {
  const int part = blockIdx.x & 7;
  const int bp = blockIdx.x >> 3;
  const int lo = part * (N_NODES / 8);
  const int hi = lo + (N_NODES / 8);
  for (int i = bp * 256 + threadIdx.x; i < N_EDGES; i += FILL_BPP * 256) {
    int d = dst[i];
    if (d >= lo && d < hi) {
      int p = atomicAdd(&cursor[d], 1);
      esrc[p] = src[i];
    }
  }
}

// ---------------- x (fp32) -> f16 hi/lo planes ----------------

__global__ void k_xcvt(const float* __restrict__ x, _Float16* __restrict__ x1,
                       _Float16* __restrict__ x2) {
  int i = blockIdx.x * blockDim.x + threadIdx.x;
  if (i < (N_NODES * DIM) / 4) {
    float4 v = reinterpret_cast<const float4*>(x)[i];
    union { _Float16 h[4]; uint2 u; } a, b;
    float vv[4] = {v.x, v.y, v.z, v.w};
#pragma unroll
    for (int j = 0; j < 4; ++j) {
      _Float16 h1 = (_Float16)vv[j];
      a.h[j] = h1;
      b.h[j] = (_Float16)(vv[j] - (float)h1);
    }
    reinterpret_cast<uint2*>(x1)[i] = a.u;
    reinterpret_cast<uint2*>(x2)[i] = b.u;
  }
}

// ---------------- weight pack: frag-major f16 hi/lo ----------------
// Per layer mats {0:ws_hi, 1:ws_lo, 2:wn_hi, 3:wn_lo};
// halfs index: (((m*4 + t)*8 + f)*64 + lane)*8 + j
// holds W[k = t*32 + (lane>>4)*8 + j][col = f*16 + (lane&15)]

#define WP_LAYER (4 * 4 * 8 * 64 * 8)  // 65536 halfs / layer
#define WP_MAT (4 * 8 * 64 * 8)        // 16384 halfs / matrix

__global__ void k_wpack(const float* __restrict__ ws0, const float* __restrict__ wn0,
                        const float* __restrict__ ws1, const float* __restrict__ wn1,
                        const float* __restrict__ ws2, const float* __restrict__ wn2,
                        const float* __restrict__ ws3, const float* __restrict__ wn3,
                        _Float16* __restrict__ wp) {
  int tid = blockIdx.x * 256 + threadIdx.x;  // 0..32767
  int l = tid & 63;
  int f = (tid >> 6) & 7;
  int t = (tid >> 9) & 3;
  int m = (tid >> 11) & 3;
  int layer = tid >> 13;
  const float* srcs[8] = {ws0, wn0, ws1, wn1, ws2, wn2, ws3, wn3};
  const float* src = srcs[layer * 2 + (m >> 1)];
  int isLo = m & 1;
  _Float16* dstp = wp + (size_t)layer * WP_LAYER + ((((m * 4 + t) * 8 + f) * 64 + l) * 8);
  int k0 = t * 32 + (l >> 4) * 8;
  int col = f * 16 + (l & 15);
#pragma unroll
  for (int j = 0; j < 8; ++j) {
    float v = src[(k0 + j) * DIM + col];
    _Float16 h1 = (_Float16)v;
    dstp[j] = isLo ? (_Float16)(v - (float)h1) : h1;
  }
}

// ---------------- aggregation: one wave per node, f16 gather, unroll 4 ----------------

__device__ __forceinline__ float f16lo(unsigned w) {
  union { unsigned u; _Float16 h[2]; } c;
  c.u = w;
  return (float)c.h[0];
}
__device__ __forceinline__ float f16hi(unsigned w) {
  union { unsigned u; _Float16 h[2]; } c;
  c.u = w;
  return (float)c.h[1];
}

__global__ void k_agg_f16(const _Float16* __restrict__ h1, const int* __restrict__ offs,
                          const int* __restrict__ esrc, const float* __restrict__ deg_inv,
                          _Float16* __restrict__ m1) {
  int wid = (blockIdx.x * blockDim.x + threadIdx.x) >> 6;  // node id
  int lane = threadIdx.x & 63;
  if (wid >= N_NODES) return;
  const unsigned* H = reinterpret_cast<const unsigned*>(h1);  // row = 64 u32
  int beg = offs[wid], end = offs[wid + 1];
  float x0 = 0.f, y0 = 0.f, x1 = 0.f, y1 = 0.f;
  float x2 = 0.f, y2 = 0.f, x3 = 0.f, y3 = 0.f;
  int e = beg;
  for (; e + 3 < end; e += 4) {
    int s0 = esrc[e], s1 = esrc[e + 1], s2 = esrc[e + 2], s3 = esrc[e + 3];
    unsigned w0 = H[(size_t)s0 * 64 + lane];
    unsigned w1 = H[(size_t)s1 * 64 + lane];
    unsigned w2 = H[(size_t)s2 * 64 + lane];
    unsigned w3 = H[(size_t)s3 * 64 + lane];
    x0 += f16lo(w0); y0 += f16hi(w0);
    x1 += f16lo(w1); y1 += f16hi(w1);
    x2 += f16lo(w2); y2 += f16hi(w2);
    x3 += f16lo(w3); y3 += f16hi(w3);
  }
  for (; e < end; ++e) {
    unsigned w0 = H[(size_t)esrc[e] * 64 + lane];
    x0 += f16lo(w0); y0 += f16hi(w0);
  }
  float di = deg_inv[wid];
  float rx = (x0 + x1 + x2 + x3) * di;
  float ry = (y0 + y1 + y2 + y3) * di;
  union { unsigned u; _Float16 h[2]; } o;
  o.h[0] = (_Float16)rx;
  o.h[1] = (_Float16)ry;
  reinterpret_cast<unsigned*>(m1)[(size_t)wid * 64 + lane] = o.u;
}

// ---------------- MFMA dual-GEMM, f16 hi/lo split ----------------
// out = act(h@ws + mean@wn + b); h = h1+h2 (f16 planes), mean = m1 (f16).
// acc += h1*ws1 + h2*ws1 + h1*ws2 + m1*wn1 + m1*wn2   (5 MFMAs per frag)
// Block = 256 threads = 4 waves; wave computes 64 rows x 128 cols.

template <int RELU, int LAST>
__global__ __launch_bounds__(256) void k_gemm_f16(
    const _Float16* __restrict__ hp1, const _Float16* __restrict__ hp2,
    const _Float16* __restrict__ mp1, const _Float16* __restrict__ wp,
    const float* __restrict__ bias, float* __restrict__ outf,
    _Float16* __restrict__ o1, _Float16* __restrict__ o2) {
  const int lane = threadIdx.x & 63;
  const int wv = threadIdx.x >> 6;
  const int row0 = blockIdx.x * 256 + wv * 64;
  const int lr = lane & 15;  // row-in-frag (A) / col (B,C)
  const int lg = lane >> 4;  // k-group (A,B) / row-group (C)

  f32x4 acc[4][8];
#pragma unroll
  for (int i = 0; i < 4; ++i)
#pragma unroll
    for (int j = 0; j < 8; ++j) acc[i][j] = (f32x4){0.f, 0.f, 0.f, 0.f};

  const _Float16* WS1 = wp;                 // ws hi
  const _Float16* WS2 = wp + WP_MAT;        // ws lo
  const _Float16* WN1 = wp + 2 * WP_MAT;    // wn hi
  const _Float16* WN2 = wp + 3 * WP_MAT;    // wn lo

  for (int t = 0; t < 4; ++t) {
    f16x8 a1[4], a2[4], am[4];
#pragma unroll
    for (int ri = 0; ri < 4; ++ri) {
      int row = row0 + ri * 16 + lr;
      row = min(row, N_NODES - 1);
      size_t off = (size_t)row * DIM + t * 32 + lg * 8;
      a1[ri] = *reinterpret_cast<const f16x8*>(hp1 + off);
      a2[ri] = *reinterpret_cast<const f16x8*>(hp2 + off);
      am[ri] = *reinterpret_cast<const f16x8*>(mp1 + off);
    }
#pragma unroll
    for (int f = 0; f < 8; ++f) {
      size_t boff = (size_t)((t * 8 + f) * 64 + lane) * 8;
      f16x8 bs1 = *reinterpret_cast<const f16x8*>(WS1 + boff);
      f16x8 bs2 = *reinterpret_cast<const f16x8*>(WS2 + boff);
      f16x8 bn1 = *reinterpret_cast<const f16x8*>(WN1 + boff);
      f16x8 bn2 = *reinterpret_cast<const f16x8*>(WN2 + boff);
#pragma unroll
      for (int ri = 0; ri < 4; ++ri) {
        acc[ri][f] = __builtin_amdgcn_mfma_f32_16x16x32_f16(a1[ri], bs1, acc[ri][f], 0, 0, 0);
        acc[ri][f] = __builtin_amdgcn_mfma_f32_16x16x32_f16(a2[ri], bs1, acc[ri][f], 0, 0, 0);
        acc[ri][f] = __builtin_amdgcn_mfma_f32_16x16x32_f16(a1[ri], bs2, acc[ri][f], 0, 0, 0);
        acc[ri][f] = __builtin_amdgcn_mfma_f32_16x16x32_f16(am[ri], bn1, acc[ri][f], 0, 0, 0);
        acc[ri][f] = __builtin_amdgcn_mfma_f32_16x16x32_f16(am[ri], bn2, acc[ri][f], 0, 0, 0);
      }
    }
  }

  // epilogue: C/D layout col=lane&15, row=(lane>>4)*4+reg
  float bv[8];
#pragma unroll
  for (int f = 0; f < 8; ++f) bv[f] = bias[f * 16 + lr];
#pragma unroll
  for (int ri = 0; ri < 4; ++ri)
#pragma unroll
    for (int f = 0; f < 8; ++f)
#pragma unroll
      for (int r = 0; r < 4; ++r) {
        int row = row0 + ri * 16 + lg * 4 + r;
        if (row < N_NODES) {
          float v = acc[ri][f][r] + bv[f];
          if (RELU) v = fmaxf(v, 0.f);
          size_t idx = (size_t)row * DIM + f * 16 + lr;
          if (LAST) {
            outf[idx] = v;
          } else {
            _Float16 hi = (_Float16)v;
            o1[idx] = hi;
            o2[idx] = (_Float16)(v - (float)hi);
          }
        }
      }
}

// ---------------- driver ----------------

extern "C" void kernel_launch(void* const* d_in, const int* in_sizes, int n_in,
                              void* d_out, int out_size, void* d_ws, size_t ws_size,
                              hipStream_t stream) {
  const float* x = (const float*)d_in[0];
  const int* src = (const int*)d_in[1];
  const int* dst = (const int*)d_in[2];
  const float* Ws[4];
  const float* Wn[4];
  const float* Bi[4];
  for (int i = 0; i < 4; ++i) {
    Ws[i] = (const float*)d_in[3 + 3 * i];
    Wn[i] = (const float*)d_in[4 + 3 * i];
    Bi[i] = (const float*)d_in[5 + 3 * i];
  }
  float* out = (float*)d_out;

  char* p = (char*)d_ws;
  auto take = [&](size_t bytes) {
    void* r = (void*)p;
    p += (bytes + 255) & ~(size_t)255;
    return r;
  };
  int* cnt = (int*)take((size_t)N_NODES * 4);
  int* offs = (int*)take((size_t)(N_NODES + 1) * 4);
  int* cursor = (int*)take((size_t)N_NODES * 4);
  int* partials = (int*)take(128 * 4);
  float* deg_inv = (float*)take((size_t)N_NODES * 4);
  int* esrc = (int*)take((size_t)N_EDGES * 4);
  _Float16* hA1 = (_Float16*)take((size_t)N_NODES * DIM * 2);
  _Float16* hA2 = (_Float16*)take((size_t)N_NODES * DIM * 2);
  _Float16* hB1 = (_Float16*)take((size_t)N_NODES * DIM * 2);
  _Float16* hB2 = (_Float16*)take((size_t)N_NODES * DIM * 2);
  _Float16* m1 = (_Float16*)take((size_t)N_NODES * DIM * 2);
  _Float16* wpk = (_Float16*)take((size_t)4 * WP_LAYER * 2);

  const int NB = (N_NODES + 1023) / 1024;  // 98

  // CSR build (edges are layer-invariant)
  k_zero<<<(N_NODES + 255) / 256, 256, 0, stream>>>(cnt, N_NODES);
  k_count<<<(N_EDGES + 255) / 256, 256, 0, stream>>>(dst, cnt);
  k_scan_blk<<<NB, 1024, 0, stream>>>(cnt, offs, partials);
  k_scan_part<<<1, 128, 0, stream>>>(partials, NB);
  k_scan_add<<<(N_NODES + 255) / 256, 256, 0, stream>>>(offs, partials);
  k_prep<<<(N_NODES + 255) / 256, 256, 0, stream>>>(offs, cnt, cursor, deg_inv);
  k_fill8<<<8 * FILL_BPP, 256, 0, stream>>>(src, dst, cursor, esrc);

  // input conversion + weight pack
  k_xcvt<<<(N_NODES * DIM / 4 + 255) / 256, 256, 0, stream>>>(x, hA1, hA2);
  k_wpack<<<128, 256, 0, stream>>>(Ws[0], Wn[0], Ws[1], Wn[1], Ws[2], Wn[2], Ws[3], Wn[3],
                                   wpk);

  const int AGG_BLOCKS = (N_NODES + 3) / 4;       // 4 waves/block, 1 node/wave
  const int GEMM_BLOCKS = (N_NODES + 255) / 256;  // 256 rows/block (64/wave)

  _Float16 *h1 = hA1, *h2 = hA2, *n1 = hB1, *n2 = hB2;
  for (int l = 0; l < 4; ++l) {
    k_agg_f16<<<AGG_BLOCKS, 256, 0, stream>>>(h1, offs, esrc, deg_inv, m1);
    const _Float16* wl = wpk + (size_t)l * WP_LAYER;
    if (l < 3) {
      k_gemm_f16<1, 0><<<GEMM_BLOCKS, 256, 0, stream>>>(h1, h2, m1, wl, Bi[l], nullptr,
                                                        n1, n2);
      _Float16* t1 = h1; h1 = n1; n1 = t1;
      _Float16* t2 = h2; h2 = n2; n2 = t2;
    } else {
      k_gemm_f16<0, 1><<<GEMM_BLOCKS, 256, 0, stream>>>(h1, h2, m1, wl, Bi[l], out,
                                                        nullptr, nullptr);
    }
  }
}

// Round 4
// 644.231 us; speedup vs baseline: 2.4474x; 1.1317x over previous
//
#include <hip/hip_runtime.h>

#define N_NODES 100000
#define N_EDGES 1600000
#define DIM 128

typedef __attribute__((ext_vector_type(8))) _Float16 f16x8;  // MFMA A/B frag (4 VGPRs)
typedef __attribute__((ext_vector_type(4))) float f32x4;     // MFMA C/D frag

// ---------------- CSR build ----------------

__global__ void k_zero(int* __restrict__ p, int n) {
  int i = blockIdx.x * blockDim.x + threadIdx.x;
  if (i < n) p[i] = 0;
}

__global__ void k_count(const int* __restrict__ dst, int* __restrict__ cnt) {
  int i = blockIdx.x * blockDim.x + threadIdx.x;
  if (i < N_EDGES) atomicAdd(&cnt[dst[i]], 1);
}

__global__ void k_scan_blk(const int* __restrict__ cnt, int* __restrict__ offs,
                           int* __restrict__ partials) {
  int tid = threadIdx.x;
  int gid = blockIdx.x * 1024 + tid;
  int v = (gid < N_NODES) ? cnt[gid] : 0;
  int lane = tid & 63, w = tid >> 6;
  int s = v;
#pragma unroll
  for (int d = 1; d < 64; d <<= 1) {
    int t = __shfl_up(s, d);
    if (lane >= d) s += t;
  }
  __shared__ int wsum[16];
  if (lane == 63) wsum[w] = s;
  __syncthreads();
  if (tid < 16) {
    int t2 = wsum[tid];
#pragma unroll
    for (int d = 1; d < 16; d <<= 1) {
      int u = __shfl_up(t2, d);
      if (tid >= d) t2 += u;
    }
    wsum[tid] = t2;
  }
  __syncthreads();
  if (w > 0) s += wsum[w - 1];
  if (gid < N_NODES) offs[gid + 1] = s;
  if (tid == 1023) partials[blockIdx.x] = s;
}

__global__ void k_scan_part(int* __restrict__ partials, int nb) {
  __shared__ int tmp[128];
  int tid = threadIdx.x;
  tmp[tid] = (tid < nb) ? partials[tid] : 0;
  __syncthreads();
  for (int d = 1; d < 128; d <<= 1) {
    int t = (tid >= d) ? tmp[tid - d] : 0;
    __syncthreads();
    tmp[tid] += t;
    __syncthreads();
  }
  if (tid < nb) partials[tid] = (tid > 0) ? tmp[tid - 1] : 0;  // exclusive
}

__global__ void k_scan_add(int* __restrict__ offs, const int* __restrict__ partials) {
  int i = blockIdx.x * blockDim.x + threadIdx.x;
  if (i == 0) offs[0] = 0;
  if (i < N_NODES) offs[i + 1] += partials[i >> 10];
}

__global__ void k_prep(const int* __restrict__ offs, const int* __restrict__ cnt,
                       int* __restrict__ cursor, float* __restrict__ deg_inv) {
  int i = blockIdx.x * blockDim.x + threadIdx.x;
  if (i < N_NODES) {
    cursor[i] = offs[i];
    deg_inv[i] = 1.0f / (float)max(cnt[i], 1);
  }
}

// XCD-partitioned fill: block handles only dst in its partition (blockIdx%8).
#define FILL_BPP 224  // blocks per partition
__global__ void k_fill8(const int* __restrict__ src, const int* __restrict__ dst,
                        int* __restrict__ cursor, int* __restrict__ esrc) {
  const int part = blockIdx.x & 7;
  const int bp = blockIdx.x >> 3;
  const int lo = part * (N_NODES / 8);
  const int hi = lo + (N_NODES / 8);
  for (int i = bp * 256 + threadIdx.x; i < N_EDGES; i += FILL_BPP * 256) {
    int d = dst[i];
    if (d >= lo && d < hi) {
      int p = atomicAdd(&cursor[d], 1);
      esrc[p] = src[i];
    }
  }
}

// ---------------- x (fp32) -> f16 hi/lo planes ----------------

__global__ void k_xcvt(const float* __restrict__ x, _Float16* __restrict__ x1,
                       _Float16* __restrict__ x2) {
  int i = blockIdx.x * blockDim.x + threadIdx.x;
  if (i < (N_NODES * DIM) / 4) {
    float4 v = reinterpret_cast<const float4*>(x)[i];
    union { _Float16 h[4]; uint2 u; } a, b;
    float vv[4] = {v.x, v.y, v.z, v.w};
#pragma unroll
    for (int j = 0; j < 4; ++j) {
      _Float16 h1 = (_Float16)vv[j];
      a.h[j] = h1;
      b.h[j] = (_Float16)(vv[j] - (float)h1);
    }
    reinterpret_cast<uint2*>(x1)[i] = a.u;
    reinterpret_cast<uint2*>(x2)[i] = b.u;
  }
}

// ---------------- weight pack: frag-major f16 hi/lo ----------------
// Per layer mats {0:ws_hi, 1:ws_lo, 2:wn_hi, 3:wn_lo};
// halfs index: (((m*4 + t)*8 + f)*64 + lane)*8 + j
// holds W[k = t*32 + (lane>>4)*8 + j][col = f*16 + (lane&15)]

#define WP_LAYER (4 * 4 * 8 * 64 * 8)  // 65536 halfs / layer
#define WP_MAT (4 * 8 * 64 * 8)        // 16384 halfs / matrix

__global__ void k_wpack(const float* __restrict__ ws0, const float* __restrict__ wn0,
                        const float* __restrict__ ws1, const float* __restrict__ wn1,
                        const float* __restrict__ ws2, const float* __restrict__ wn2,
                        const float* __restrict__ ws3, const float* __restrict__ wn3,
                        _Float16* __restrict__ wp) {
  int tid = blockIdx.x * 256 + threadIdx.x;  // 0..32767
  int l = tid & 63;
  int f = (tid >> 6) & 7;
  int t = (tid >> 9) & 3;
  int m = (tid >> 11) & 3;
  int layer = tid >> 13;
  const float* srcs[8] = {ws0, wn0, ws1, wn1, ws2, wn2, ws3, wn3};
  const float* src = srcs[layer * 2 + (m >> 1)];
  int isLo = m & 1;
  _Float16* dstp = wp + (size_t)layer * WP_LAYER + ((((m * 4 + t) * 8 + f) * 64 + l) * 8);
  int k0 = t * 32 + (l >> 4) * 8;
  int col = f * 16 + (l & 15);
#pragma unroll
  for (int j = 0; j < 8; ++j) {
    float v = src[(k0 + j) * DIM + col];
    _Float16 h1 = (_Float16)v;
    dstp[j] = isLo ? (_Float16)(v - (float)h1) : h1;
  }
}

// ---------------- aggregation: one wave per node, f16 gather, unroll 8 ----------------

__device__ __forceinline__ float f16lo(unsigned w) {
  union { unsigned u; _Float16 h[2]; } c;
  c.u = w;
  return (float)c.h[0];
}
__device__ __forceinline__ float f16hi(unsigned w) {
  union { unsigned u; _Float16 h[2]; } c;
  c.u = w;
  return (float)c.h[1];
}

__global__ void k_agg_f16(const _Float16* __restrict__ h1, const int* __restrict__ offs,
                          const int* __restrict__ esrc, const float* __restrict__ deg_inv,
                          _Float16* __restrict__ m1) {
  int wid = (blockIdx.x * blockDim.x + threadIdx.x) >> 6;  // node id
  int lane = threadIdx.x & 63;
  if (wid >= N_NODES) return;
  const unsigned* H = reinterpret_cast<const unsigned*>(h1);  // row = 64 u32
  int beg = offs[wid], end = offs[wid + 1];
  float xs[8] = {0.f, 0.f, 0.f, 0.f, 0.f, 0.f, 0.f, 0.f};
  float ys[8] = {0.f, 0.f, 0.f, 0.f, 0.f, 0.f, 0.f, 0.f};
  int e = beg;
  for (; e + 7 < end; e += 8) {
    int s[8];
#pragma unroll
    for (int j = 0; j < 8; ++j) s[j] = esrc[e + j];
    unsigned w[8];
#pragma unroll
    for (int j = 0; j < 8; ++j) w[j] = H[(size_t)s[j] * 64 + lane];
#pragma unroll
    for (int j = 0; j < 8; ++j) {
      xs[j] += f16lo(w[j]);
      ys[j] += f16hi(w[j]);
    }
  }
  for (; e + 1 < end; e += 2) {
    unsigned w0 = H[(size_t)esrc[e] * 64 + lane];
    unsigned w1 = H[(size_t)esrc[e + 1] * 64 + lane];
    xs[0] += f16lo(w0); ys[0] += f16hi(w0);
    xs[1] += f16lo(w1); ys[1] += f16hi(w1);
  }
  if (e < end) {
    unsigned w0 = H[(size_t)esrc[e] * 64 + lane];
    xs[2] += f16lo(w0); ys[2] += f16hi(w0);
  }
  float di = deg_inv[wid];
  float rx = ((xs[0] + xs[1]) + (xs[2] + xs[3])) + ((xs[4] + xs[5]) + (xs[6] + xs[7]));
  float ry = ((ys[0] + ys[1]) + (ys[2] + ys[3])) + ((ys[4] + ys[5]) + (ys[6] + ys[7]));
  rx *= di;
  ry *= di;
  union { unsigned u; _Float16 h[2]; } o;
  o.h[0] = (_Float16)rx;
  o.h[1] = (_Float16)ry;
  reinterpret_cast<unsigned*>(m1)[(size_t)wid * 64 + lane] = o.u;
}

// ---------------- MFMA dual-GEMM, f16 hi/lo split ----------------
// out = act(h@ws + mean@wn + b); h = h1+h2 (f16 planes), mean = m1 (f16).
// acc += h1*ws1 + h2*ws1 + h1*ws2 + m1*wn1 + m1*wn2   (5 MFMAs per frag)
// Block = 256 threads = 4 waves; wave computes 32 rows x 128 cols (2x8 frags).
// 782 blocks -> 3128 waves: latency hidden by TLP (round-3 was 9% occupancy).

template <int RELU, int LAST>
__global__ __launch_bounds__(256) void k_gemm_f16(
    const _Float16* __restrict__ hp1, const _Float16* __restrict__ hp2,
    const _Float16* __restrict__ mp1, const _Float16* __restrict__ wp,
    const float* __restrict__ bias, float* __restrict__ outf,
    _Float16* __restrict__ o1, _Float16* __restrict__ o2) {
  const int lane = threadIdx.x & 63;
  const int wv = threadIdx.x >> 6;
  const int row0 = blockIdx.x * 128 + wv * 32;
  const int lr = lane & 15;  // row-in-frag (A) / col (B,C)
  const int lg = lane >> 4;  // k-group (A,B) / row-group (C)

  f32x4 acc[2][8];
#pragma unroll
  for (int i = 0; i < 2; ++i)
#pragma unroll
    for (int j = 0; j < 8; ++j) acc[i][j] = (f32x4){0.f, 0.f, 0.f, 0.f};

  const _Float16* WS1 = wp;               // ws hi
  const _Float16* WS2 = wp + WP_MAT;      // ws lo
  const _Float16* WN1 = wp + 2 * WP_MAT;  // wn hi
  const _Float16* WN2 = wp + 3 * WP_MAT;  // wn lo

  for (int t = 0; t < 4; ++t) {
    f16x8 a1[2], a2[2], am[2];
#pragma unroll
    for (int ri = 0; ri < 2; ++ri) {
      int row = row0 + ri * 16 + lr;
      row = min(row, N_NODES - 1);
      size_t off = (size_t)row * DIM + t * 32 + lg * 8;
      a1[ri] = *reinterpret_cast<const f16x8*>(hp1 + off);
      a2[ri] = *reinterpret_cast<const f16x8*>(hp2 + off);
      am[ri] = *reinterpret_cast<const f16x8*>(mp1 + off);
    }
#pragma unroll
    for (int f = 0; f < 8; ++f) {
      size_t boff = (size_t)((t * 8 + f) * 64 + lane) * 8;
      f16x8 bs1 = *reinterpret_cast<const f16x8*>(WS1 + boff);
      f16x8 bs2 = *reinterpret_cast<const f16x8*>(WS2 + boff);
      f16x8 bn1 = *reinterpret_cast<const f16x8*>(WN1 + boff);
      f16x8 bn2 = *reinterpret_cast<const f16x8*>(WN2 + boff);
#pragma unroll
      for (int ri = 0; ri < 2; ++ri) {
        acc[ri][f] = __builtin_amdgcn_mfma_f32_16x16x32_f16(a1[ri], bs1, acc[ri][f], 0, 0, 0);
        acc[ri][f] = __builtin_amdgcn_mfma_f32_16x16x32_f16(a2[ri], bs1, acc[ri][f], 0, 0, 0);
        acc[ri][f] = __builtin_amdgcn_mfma_f32_16x16x32_f16(a1[ri], bs2, acc[ri][f], 0, 0, 0);
        acc[ri][f] = __builtin_amdgcn_mfma_f32_16x16x32_f16(am[ri], bn1, acc[ri][f], 0, 0, 0);
        acc[ri][f] = __builtin_amdgcn_mfma_f32_16x16x32_f16(am[ri], bn2, acc[ri][f], 0, 0, 0);
      }
    }
  }

  // epilogue: C/D layout col=lane&15, row=(lane>>4)*4+reg
  float bv[8];
#pragma unroll
  for (int f = 0; f < 8; ++f) bv[f] = bias[f * 16 + lr];
#pragma unroll
  for (int ri = 0; ri < 2; ++ri)
#pragma unroll
    for (int f = 0; f < 8; ++f)
#pragma unroll
      for (int r = 0; r < 4; ++r) {
        int row = row0 + ri * 16 + lg * 4 + r;
        if (row < N_NODES) {
          float v = acc[ri][f][r] + bv[f];
          if (RELU) v = fmaxf(v, 0.f);
          size_t idx = (size_t)row * DIM + f * 16 + lr;
          if (LAST) {
            outf[idx] = v;
          } else {
            _Float16 hi = (_Float16)v;
            o1[idx] = hi;
            o2[idx] = (_Float16)(v - (float)hi);
          }
        }
      }
}

// ---------------- driver ----------------

extern "C" void kernel_launch(void* const* d_in, const int* in_sizes, int n_in,
                              void* d_out, int out_size, void* d_ws, size_t ws_size,
                              hipStream_t stream) {
  const float* x = (const float*)d_in[0];
  const int* src = (const int*)d_in[1];
  const int* dst = (const int*)d_in[2];
  const float* Ws[4];
  const float* Wn[4];
  const float* Bi[4];
  for (int i = 0; i < 4; ++i) {
    Ws[i] = (const float*)d_in[3 + 3 * i];
    Wn[i] = (const float*)d_in[4 + 3 * i];
    Bi[i] = (const float*)d_in[5 + 3 * i];
  }
  float* out = (float*)d_out;

  char* p = (char*)d_ws;
  auto take = [&](size_t bytes) {
    void* r = (void*)p;
    p += (bytes + 255) & ~(size_t)255;
    return r;
  };
  int* cnt = (int*)take((size_t)N_NODES * 4);
  int* offs = (int*)take((size_t)(N_NODES + 1) * 4);
  int* cursor = (int*)take((size_t)N_NODES * 4);
  int* partials = (int*)take(128 * 4);
  float* deg_inv = (float*)take((size_t)N_NODES * 4);
  int* esrc = (int*)take((size_t)N_EDGES * 4);
  _Float16* hA1 = (_Float16*)take((size_t)N_NODES * DIM * 2);
  _Float16* hA2 = (_Float16*)take((size_t)N_NODES * DIM * 2);
  _Float16* hB1 = (_Float16*)take((size_t)N_NODES * DIM * 2);
  _Float16* hB2 = (_Float16*)take((size_t)N_NODES * DIM * 2);
  _Float16* m1 = (_Float16*)take((size_t)N_NODES * DIM * 2);
  _Float16* wpk = (_Float16*)take((size_t)4 * WP_LAYER * 2);

  const int NB = (N_NODES + 1023) / 1024;  // 98

  // CSR build (edges are layer-invariant)
  k_zero<<<(N_NODES + 255) / 256, 256, 0, stream>>>(cnt, N_NODES);
  k_count<<<(N_EDGES + 255) / 256, 256, 0, stream>>>(dst, cnt);
  k_scan_blk<<<NB, 1024, 0, stream>>>(cnt, offs, partials);
  k_scan_part<<<1, 128, 0, stream>>>(partials, NB);
  k_scan_add<<<(N_NODES + 255) / 256, 256, 0, stream>>>(offs, partials);
  k_prep<<<(N_NODES + 255) / 256, 256, 0, stream>>>(offs, cnt, cursor, deg_inv);
  k_fill8<<<8 * FILL_BPP, 256, 0, stream>>>(src, dst, cursor, esrc);

  // input conversion + weight pack
  k_xcvt<<<(N_NODES * DIM / 4 + 255) / 256, 256, 0, stream>>>(x, hA1, hA2);
  k_wpack<<<128, 256, 0, stream>>>(Ws[0], Wn[0], Ws[1], Wn[1], Ws[2], Wn[2], Ws[3], Wn[3],
                                   wpk);

  const int AGG_BLOCKS = (N_NODES + 3) / 4;       // 4 waves/block, 1 node/wave
  const int GEMM_BLOCKS = (N_NODES + 127) / 128;  // 128 rows/block (32/wave)

  _Float16 *h1 = hA1, *h2 = hA2, *n1 = hB1, *n2 = hB2;
  for (int l = 0; l < 4; ++l) {
    k_agg_f16<<<AGG_BLOCKS, 256, 0, stream>>>(h1, offs, esrc, deg_inv, m1);
    const _Float16* wl = wpk + (size_t)l * WP_LAYER;
    if (l < 3) {
      k_gemm_f16<1, 0><<<GEMM_BLOCKS, 256, 0, stream>>>(h1, h2, m1, wl, Bi[l], nullptr,
                                                        n1, n2);
      _Float16* t1 = h1; h1 = n1; n1 = t1;
      _Float16* t2 = h2; h2 = n2; n2 = t2;
    } else {
      k_gemm_f16<0, 1><<<GEMM_BLOCKS, 256, 0, stream>>>(h1, h2, m1, wl, Bi[l], out,
                                                        nullptr, nullptr);
    }
  }
}

// Round 5
// 607.703 us; speedup vs baseline: 2.5945x; 1.0601x over previous
//
#include <hip/hip_runtime.h>

#define N_NODES 100000
#define N_EDGES 1600000
#define DIM 128

typedef __attribute__((ext_vector_type(8))) _Float16 f16x8;  // MFMA A/B frag (4 VGPRs)
typedef __attribute__((ext_vector_type(4))) float f32x4;     // MFMA C/D frag

// ---------------- CSR build ----------------

__global__ void k_zero(int* __restrict__ p, int n) {
  int i = blockIdx.x * blockDim.x + threadIdx.x;
  if (i < n) p[i] = 0;
}

__global__ void k_count(const int* __restrict__ dst, int* __restrict__ cnt) {
  int i = blockIdx.x * blockDim.x + threadIdx.x;
  if (i < N_EDGES) atomicAdd(&cnt[dst[i]], 1);
}

__global__ void k_scan_blk(const int* __restrict__ cnt, int* __restrict__ offs,
                           int* __restrict__ partials) {
  int tid = threadIdx.x;
  int gid = blockIdx.x * 1024 + tid;
  int v = (gid < N_NODES) ? cnt[gid] : 0;
  int lane = tid & 63, w = tid >> 6;
  int s = v;
#pragma unroll
  for (int d = 1; d < 64; d <<= 1) {
    int t = __shfl_up(s, d);
    if (lane >= d) s += t;
  }
  __shared__ int wsum[16];
  if (lane == 63) wsum[w] = s;
  __syncthreads();
  if (tid < 16) {
    int t2 = wsum[tid];
#pragma unroll
    for (int d = 1; d < 16; d <<= 1) {
      int u = __shfl_up(t2, d);
      if (tid >= d) t2 += u;
    }
    wsum[tid] = t2;
  }
  __syncthreads();
  if (w > 0) s += wsum[w - 1];
  if (gid < N_NODES) offs[gid + 1] = s;
  if (tid == 1023) partials[blockIdx.x] = s;
}

__global__ void k_scan_part(int* __restrict__ partials, int nb) {
  __shared__ int tmp[128];
  int tid = threadIdx.x;
  tmp[tid] = (tid < nb) ? partials[tid] : 0;
  __syncthreads();
  for (int d = 1; d < 128; d <<= 1) {
    int t = (tid >= d) ? tmp[tid - d] : 0;
    __syncthreads();
    tmp[tid] += t;
    __syncthreads();
  }
  if (tid < nb) partials[tid] = (tid > 0) ? tmp[tid - 1] : 0;  // exclusive
}

__global__ void k_scan_add(int* __restrict__ offs, const int* __restrict__ partials) {
  int i = blockIdx.x * blockDim.x + threadIdx.x;
  if (i == 0) offs[0] = 0;
  if (i < N_NODES) offs[i + 1] += partials[i >> 10];
}

__global__ void k_prep(const int* __restrict__ offs, const int* __restrict__ cnt,
                       int* __restrict__ cursor, float* __restrict__ deg_inv) {
  int i = blockIdx.x * blockDim.x + threadIdx.x;
  if (i < N_NODES) {
    cursor[i] = offs[i];
    deg_inv[i] = 1.0f / (float)max(cnt[i], 1);
  }
}

// XCD-partitioned fill: block handles only dst in its partition (blockIdx%8).
#define FILL_BPP 224  // blocks per partition
__global__ void k_fill8(const int* __restrict__ src, const int* __restrict__ dst,
                        int* __restrict__ cursor, int* __restrict__ esrc) {
  const int part = blockIdx.x & 7;
  const int bp = blockIdx.x >> 3;
  const int lo = part * (N_NODES / 8);
  const int hi = lo + (N_NODES / 8);
  for (int i = bp * 256 + threadIdx.x; i < N_EDGES; i += FILL_BPP * 256) {
    int d = dst[i];
    if (d >= lo && d < hi) {
      int p = atomicAdd(&cursor[d], 1);
      esrc[p] = src[i];
    }
  }
}

// ---------------- x (fp32) -> f16 hi/lo planes ----------------

__global__ void k_xcvt(const float* __restrict__ x, _Float16* __restrict__ x1,
                       _Float16* __restrict__ x2) {
  int i = blockIdx.x * blockDim.x + threadIdx.x;
  if (i < (N_NODES * DIM) / 4) {
    float4 v = reinterpret_cast<const float4*>(x)[i];
    union { _Float16 h[4]; uint2 u; } a, b;
    float vv[4] = {v.x, v.y, v.z, v.w};
#pragma unroll
    for (int j = 0; j < 4; ++j) {
      _Float16 h1 = (_Float16)vv[j];
      a.h[j] = h1;
      b.h[j] = (_Float16)(vv[j] - (float)h1);
    }
    reinterpret_cast<uint2*>(x1)[i] = a.u;
    reinterpret_cast<uint2*>(x2)[i] = b.u;
  }
}

// ---------------- weight pack: frag-major f16 hi/lo ----------------
// Per layer mats {0:ws_hi, 1:ws_lo, 2:wn_hi, 3:wn_lo};
// halfs index: (((m*4 + t)*8 + f)*64 + lane)*8 + j
// holds W[k = t*32 + (lane>>4)*8 + j][col = f*16 + (lane&15)]

#define WP_LAYER (4 * 4 * 8 * 64 * 8)  // 65536 halfs / layer
#define WP_MAT (4 * 8 * 64 * 8)        // 16384 halfs / matrix

__global__ void k_wpack(const float* __restrict__ ws0, const float* __restrict__ wn0,
                        const float* __restrict__ ws1, const float* __restrict__ wn1,
                        const float* __restrict__ ws2, const float* __restrict__ wn2,
                        const float* __restrict__ ws3, const float* __restrict__ wn3,
                        _Float16* __restrict__ wp) {
  int tid = blockIdx.x * 256 + threadIdx.x;  // 0..32767
  int l = tid & 63;
  int f = (tid >> 6) & 7;
  int t = (tid >> 9) & 3;
  int m = (tid >> 11) & 3;
  int layer = tid >> 13;
  const float* srcs[8] = {ws0, wn0, ws1, wn1, ws2, wn2, ws3, wn3};
  const float* src = srcs[layer * 2 + (m >> 1)];
  int isLo = m & 1;
  _Float16* dstp = wp + (size_t)layer * WP_LAYER + ((((m * 4 + t) * 8 + f) * 64 + l) * 8);
  int k0 = t * 32 + (l >> 4) * 8;
  int col = f * 16 + (l & 15);
#pragma unroll
  for (int j = 0; j < 8; ++j) {
    float v = src[(k0 + j) * DIM + col];
    _Float16 h1 = (_Float16)v;
    dstp[j] = isLo ? (_Float16)(v - (float)h1) : h1;
  }
}

// ---------------- aggregation: one wave per node, f16 gather, unroll 8 ----------------

__device__ __forceinline__ float f16lo(unsigned w) {
  union { unsigned u; _Float16 h[2]; } c;
  c.u = w;
  return (float)c.h[0];
}
__device__ __forceinline__ float f16hi(unsigned w) {
  union { unsigned u; _Float16 h[2]; } c;
  c.u = w;
  return (float)c.h[1];
}

__global__ void k_agg_f16(const _Float16* __restrict__ h1, const int* __restrict__ offs,
                          const int* __restrict__ esrc, const float* __restrict__ deg_inv,
                          _Float16* __restrict__ m1) {
  int wid = (blockIdx.x * blockDim.x + threadIdx.x) >> 6;  // node id
  int lane = threadIdx.x & 63;
  if (wid >= N_NODES) return;
  const unsigned* H = reinterpret_cast<const unsigned*>(h1);  // row = 64 u32
  int beg = offs[wid], end = offs[wid + 1];
  float xs[8] = {0.f, 0.f, 0.f, 0.f, 0.f, 0.f, 0.f, 0.f};
  float ys[8] = {0.f, 0.f, 0.f, 0.f, 0.f, 0.f, 0.f, 0.f};
  int e = beg;
  for (; e + 7 < end; e += 8) {
    int s[8];
#pragma unroll
    for (int j = 0; j < 8; ++j) s[j] = esrc[e + j];
    unsigned w[8];
#pragma unroll
    for (int j = 0; j < 8; ++j) w[j] = H[(size_t)s[j] * 64 + lane];
#pragma unroll
    for (int j = 0; j < 8; ++j) {
      xs[j] += f16lo(w[j]);
      ys[j] += f16hi(w[j]);
    }
  }
  for (; e + 1 < end; e += 2) {
    unsigned w0 = H[(size_t)esrc[e] * 64 + lane];
    unsigned w1 = H[(size_t)esrc[e + 1] * 64 + lane];
    xs[0] += f16lo(w0); ys[0] += f16hi(w0);
    xs[1] += f16lo(w1); ys[1] += f16hi(w1);
  }
  if (e < end) {
    unsigned w0 = H[(size_t)esrc[e] * 64 + lane];
    xs[2] += f16lo(w0); ys[2] += f16hi(w0);
  }
  float di = deg_inv[wid];
  float rx = ((xs[0] + xs[1]) + (xs[2] + xs[3])) + ((xs[4] + xs[5]) + (xs[6] + xs[7]));
  float ry = ((ys[0] + ys[1]) + (ys[2] + ys[3])) + ((ys[4] + ys[5]) + (ys[6] + ys[7]));
  rx *= di;
  ry *= di;
  union { unsigned u; _Float16 h[2]; } o;
  o.h[0] = (_Float16)rx;
  o.h[1] = (_Float16)ry;
  reinterpret_cast<unsigned*>(m1)[(size_t)wid * 64 + lane] = o.u;
}

// ---------------- MFMA dual-GEMM, f16 hi/lo split ----------------
// out = act(h@ws + mean@wn + b); h = h1+h2 (f16 planes), mean = m1 (f16).
// acc += h1*ws1 + h2*ws1 + h1*ws2 + m1*wn1 + m1*wn2   (5 MFMAs per frag)
// Block = 256 threads = 4 waves; wave = 32 rows x 64 cols (2x4 frags, 32 acc VGPR).
// Grid = 1564 blocks (782 row-tiles x 2 col-halves) -> 6256 waves.
// __launch_bounds__(256,4): pin 4 waves/SIMD (VGPR<=128); B loads batched 8-at-a-time
// ahead of their 20 MFMAs so vmcnt pipelining hides L2 latency.

template <int RELU, int LAST>
__global__ __launch_bounds__(256, 4) void k_gemm_f16(
    const _Float16* __restrict__ hp1, const _Float16* __restrict__ hp2,
    const _Float16* __restrict__ mp1, const _Float16* __restrict__ wp,
    const float* __restrict__ bias, float* __restrict__ outf,
    _Float16* __restrict__ o1, _Float16* __restrict__ o2) {
  const int lane = threadIdx.x & 63;
  const int wv = threadIdx.x >> 6;
  const int ch = blockIdx.x & 1;                       // col half: cols ch*64..ch*64+63
  const int row0 = (blockIdx.x >> 1) * 128 + wv * 32;  // wave's 32 rows
  const int lr = lane & 15;  // row-in-frag (A) / col (B,C)
  const int lg = lane >> 4;  // k-group (A,B) / row-group (C)

  f32x4 acc[2][4];  // [ri][f-local]
#pragma unroll
  for (int i = 0; i < 2; ++i)
#pragma unroll
    for (int j = 0; j < 4; ++j) acc[i][j] = (f32x4){0.f, 0.f, 0.f, 0.f};

  const _Float16* WS1 = wp;               // ws hi
  const _Float16* WS2 = wp + WP_MAT;      // ws lo
  const _Float16* WN1 = wp + 2 * WP_MAT;  // wn hi
  const _Float16* WN2 = wp + 3 * WP_MAT;  // wn lo

#pragma unroll
  for (int t = 0; t < 4; ++t) {
    // ---- A loads for this k-step (6 x 16B) ----
    f16x8 a1[2], a2[2], am[2];
#pragma unroll
    for (int ri = 0; ri < 2; ++ri) {
      int row = row0 + ri * 16 + lr;
      row = min(row, N_NODES - 1);
      size_t off = (size_t)row * DIM + t * 32 + lg * 8;
      a1[ri] = *reinterpret_cast<const f16x8*>(hp1 + off);
      a2[ri] = *reinterpret_cast<const f16x8*>(hp2 + off);
      am[ri] = *reinterpret_cast<const f16x8*>(mp1 + off);
    }
#pragma unroll
    for (int fh = 0; fh < 2; ++fh) {
      // ---- batch-load 8 B frags (2 cols-frags x 4 mats), then 20 MFMAs ----
      f16x8 bs1[2], bs2[2], bn1[2], bn2[2];
#pragma unroll
      for (int q = 0; q < 2; ++q) {
        int f = ch * 4 + fh * 2 + q;
        size_t boff = (size_t)((t * 8 + f) * 64 + lane) * 8;
        bs1[q] = *reinterpret_cast<const f16x8*>(WS1 + boff);
        bs2[q] = *reinterpret_cast<const f16x8*>(WS2 + boff);
        bn1[q] = *reinterpret_cast<const f16x8*>(WN1 + boff);
        bn2[q] = *reinterpret_cast<const f16x8*>(WN2 + boff);
      }
#pragma unroll
      for (int q = 0; q < 2; ++q) {
        int fl = fh * 2 + q;
#pragma unroll
        for (int ri = 0; ri < 2; ++ri) {
          acc[ri][fl] =
              __builtin_amdgcn_mfma_f32_16x16x32_f16(a1[ri], bs1[q], acc[ri][fl], 0, 0, 0);
          acc[ri][fl] =
              __builtin_amdgcn_mfma_f32_16x16x32_f16(a2[ri], bs1[q], acc[ri][fl], 0, 0, 0);
          acc[ri][fl] =
              __builtin_amdgcn_mfma_f32_16x16x32_f16(a1[ri], bs2[q], acc[ri][fl], 0, 0, 0);
          acc[ri][fl] =
              __builtin_amdgcn_mfma_f32_16x16x32_f16(am[ri], bn1[q], acc[ri][fl], 0, 0, 0);
          acc[ri][fl] =
              __builtin_amdgcn_mfma_f32_16x16x32_f16(am[ri], bn2[q], acc[ri][fl], 0, 0, 0);
        }
      }
    }
  }

  // epilogue: C/D layout col=lane&15, row=(lane>>4)*4+reg
  float bv[4];
#pragma unroll
  for (int fl = 0; fl < 4; ++fl) bv[fl] = bias[ch * 64 + fl * 16 + lr];
#pragma unroll
  for (int ri = 0; ri < 2; ++ri)
#pragma unroll
    for (int fl = 0; fl < 4; ++fl)
#pragma unroll
      for (int r = 0; r < 4; ++r) {
        int row = row0 + ri * 16 + lg * 4 + r;
        if (row < N_NODES) {
          float v = acc[ri][fl][r] + bv[fl];
          if (RELU) v = fmaxf(v, 0.f);
          size_t idx = (size_t)row * DIM + ch * 64 + fl * 16 + lr;
          if (LAST) {
            outf[idx] = v;
          } else {
            _Float16 hi = (_Float16)v;
            o1[idx] = hi;
            o2[idx] = (_Float16)(v - (float)hi);
          }
        }
      }
}

// ---------------- driver ----------------

extern "C" void kernel_launch(void* const* d_in, const int* in_sizes, int n_in,
                              void* d_out, int out_size, void* d_ws, size_t ws_size,
                              hipStream_t stream) {
  const float* x = (const float*)d_in[0];
  const int* src = (const int*)d_in[1];
  const int* dst = (const int*)d_in[2];
  const float* Ws[4];
  const float* Wn[4];
  const float* Bi[4];
  for (int i = 0; i < 4; ++i) {
    Ws[i] = (const float*)d_in[3 + 3 * i];
    Wn[i] = (const float*)d_in[4 + 3 * i];
    Bi[i] = (const float*)d_in[5 + 3 * i];
  }
  float* out = (float*)d_out;

  char* p = (char*)d_ws;
  auto take = [&](size_t bytes) {
    void* r = (void*)p;
    p += (bytes + 255) & ~(size_t)255;
    return r;
  };
  int* cnt = (int*)take((size_t)N_NODES * 4);
  int* offs = (int*)take((size_t)(N_NODES + 1) * 4);
  int* cursor = (int*)take((size_t)N_NODES * 4);
  int* partials = (int*)take(128 * 4);
  float* deg_inv = (float*)take((size_t)N_NODES * 4);
  int* esrc = (int*)take((size_t)N_EDGES * 4);
  _Float16* hA1 = (_Float16*)take((size_t)N_NODES * DIM * 2);
  _Float16* hA2 = (_Float16*)take((size_t)N_NODES * DIM * 2);
  _Float16* hB1 = (_Float16*)take((size_t)N_NODES * DIM * 2);
  _Float16* hB2 = (_Float16*)take((size_t)N_NODES * DIM * 2);
  _Float16* m1 = (_Float16*)take((size_t)N_NODES * DIM * 2);
  _Float16* wpk = (_Float16*)take((size_t)4 * WP_LAYER * 2);

  const int NB = (N_NODES + 1023) / 1024;  // 98

  // CSR build (edges are layer-invariant)
  k_zero<<<(N_NODES + 255) / 256, 256, 0, stream>>>(cnt, N_NODES);
  k_count<<<(N_EDGES + 255) / 256, 256, 0, stream>>>(dst, cnt);
  k_scan_blk<<<NB, 1024, 0, stream>>>(cnt, offs, partials);
  k_scan_part<<<1, 128, 0, stream>>>(partials, NB);
  k_scan_add<<<(N_NODES + 255) / 256, 256, 0, stream>>>(offs, partials);
  k_prep<<<(N_NODES + 255) / 256, 256, 0, stream>>>(offs, cnt, cursor, deg_inv);
  k_fill8<<<8 * FILL_BPP, 256, 0, stream>>>(src, dst, cursor, esrc);

  // input conversion + weight pack
  k_xcvt<<<(N_NODES * DIM / 4 + 255) / 256, 256, 0, stream>>>(x, hA1, hA2);
  k_wpack<<<128, 256, 0, stream>>>(Ws[0], Wn[0], Ws[1], Wn[1], Ws[2], Wn[2], Ws[3], Wn[3],
                                   wpk);

  const int AGG_BLOCKS = (N_NODES + 3) / 4;  // 4 waves/block, 1 node/wave
  const int GEMM_BLOCKS = ((N_NODES + 127) / 128) * 2;  // 782 row-tiles x 2 col-halves

  _Float16 *h1 = hA1, *h2 = hA2, *n1 = hB1, *n2 = hB2;
  for (int l = 0; l < 4; ++l) {
    k_agg_f16<<<AGG_BLOCKS, 256, 0, stream>>>(h1, offs, esrc, deg_inv, m1);
    const _Float16* wl = wpk + (size_t)l * WP_LAYER;
    if (l < 3) {
      k_gemm_f16<1, 0><<<GEMM_BLOCKS, 256, 0, stream>>>(h1, h2, m1, wl, Bi[l], nullptr,
                                                        n1, n2);
      _Float16* t1 = h1; h1 = n1; n1 = t1;
      _Float16* t2 = h2; h2 = n2; n2 = t2;
    } else {
      k_gemm_f16<0, 1><<<GEMM_BLOCKS, 256, 0, stream>>>(h1, h2, m1, wl, Bi[l], out,
                                                        nullptr, nullptr);
    }
  }
}

// Round 6
// 586.044 us; speedup vs baseline: 2.6904x; 1.0370x over previous
//
#include <hip/hip_runtime.h>

#define N_NODES 100000
#define N_EDGES 1600000
#define DIM 128

typedef __attribute__((ext_vector_type(8))) _Float16 f16x8;  // MFMA A/B frag (4 VGPRs)
typedef __attribute__((ext_vector_type(4))) float f32x4;     // MFMA C/D frag

// async global->LDS DMA, 16B per lane (dest = wave-uniform base + lane*16)
__device__ __forceinline__ void stage16(const _Float16* g, _Float16* l) {
  __builtin_amdgcn_global_load_lds(
      (const __attribute__((address_space(1))) void*)g,
      (__attribute__((address_space(3))) void*)l, 16, 0, 0);
}

// ---------------- CSR build ----------------

__global__ void k_zero(int* __restrict__ p, int n) {
  int i = blockIdx.x * blockDim.x + threadIdx.x;
  if (i < n) p[i] = 0;
}

__global__ void k_count(const int* __restrict__ dst, int* __restrict__ cnt) {
  int i = blockIdx.x * blockDim.x + threadIdx.x;
  if (i < N_EDGES) atomicAdd(&cnt[dst[i]], 1);
}

__global__ void k_scan_blk(const int* __restrict__ cnt, int* __restrict__ offs,
                           int* __restrict__ partials) {
  int tid = threadIdx.x;
  int gid = blockIdx.x * 1024 + tid;
  int v = (gid < N_NODES) ? cnt[gid] : 0;
  int lane = tid & 63, w = tid >> 6;
  int s = v;
#pragma unroll
  for (int d = 1; d < 64; d <<= 1) {
    int t = __shfl_up(s, d);
    if (lane >= d) s += t;
  }
  __shared__ int wsum[16];
  if (lane == 63) wsum[w] = s;
  __syncthreads();
  if (tid < 16) {
    int t2 = wsum[tid];
#pragma unroll
    for (int d = 1; d < 16; d <<= 1) {
      int u = __shfl_up(t2, d);
      if (tid >= d) t2 += u;
    }
    wsum[tid] = t2;
  }
  __syncthreads();
  if (w > 0) s += wsum[w - 1];
  if (gid < N_NODES) offs[gid + 1] = s;
  if (tid == 1023) partials[blockIdx.x] = s;
}

__global__ void k_scan_part(int* __restrict__ partials, int nb) {
  __shared__ int tmp[128];
  int tid = threadIdx.x;
  tmp[tid] = (tid < nb) ? partials[tid] : 0;
  __syncthreads();
  for (int d = 1; d < 128; d <<= 1) {
    int t = (tid >= d) ? tmp[tid - d] : 0;
    __syncthreads();
    tmp[tid] += t;
    __syncthreads();
  }
  if (tid < nb) partials[tid] = (tid > 0) ? tmp[tid - 1] : 0;  // exclusive
}

__global__ void k_scan_add(int* __restrict__ offs, const int* __restrict__ partials) {
  int i = blockIdx.x * blockDim.x + threadIdx.x;
  if (i == 0) offs[0] = 0;
  if (i < N_NODES) offs[i + 1] += partials[i >> 10];
}

__global__ void k_prep(const int* __restrict__ offs, const int* __restrict__ cnt,
                       int* __restrict__ cursor, float* __restrict__ deg_inv) {
  int i = blockIdx.x * blockDim.x + threadIdx.x;
  if (i < N_NODES) {
    cursor[i] = offs[i];
    deg_inv[i] = 1.0f / (float)max(cnt[i], 1);
  }
}

// XCD-partitioned fill: block handles only dst in its partition (blockIdx%8).
#define FILL_BPP 224  // blocks per partition
__global__ void k_fill8(const int* __restrict__ src, const int* __restrict__ dst,
                        int* __restrict__ cursor, int* __restrict__ esrc) {
  const int part = blockIdx.x & 7;
  const int bp = blockIdx.x >> 3;
  const int lo = part * (N_NODES / 8);
  const int hi = lo + (N_NODES / 8);
  for (int i = bp * 256 + threadIdx.x; i < N_EDGES; i += FILL_BPP * 256) {
    int d = dst[i];
    if (d >= lo && d < hi) {
      int p = atomicAdd(&cursor[d], 1);
      esrc[p] = src[i];
    }
  }
}

// ---------------- x (fp32) -> f16 hi/lo planes ----------------

__global__ void k_xcvt(const float* __restrict__ x, _Float16* __restrict__ x1,
                       _Float16* __restrict__ x2) {
  int i = blockIdx.x * blockDim.x + threadIdx.x;
  if (i < (N_NODES * DIM) / 4) {
    float4 v = reinterpret_cast<const float4*>(x)[i];
    union { _Float16 h[4]; uint2 u; } a, b;
    float vv[4] = {v.x, v.y, v.z, v.w};
#pragma unroll
    for (int j = 0; j < 4; ++j) {
      _Float16 h1 = (_Float16)vv[j];
      a.h[j] = h1;
      b.h[j] = (_Float16)(vv[j] - (float)h1);
    }
    reinterpret_cast<uint2*>(x1)[i] = a.u;
    reinterpret_cast<uint2*>(x2)[i] = b.u;
  }
}

// ---------------- weight pack: frag-major f16 hi/lo ----------------
// Per layer mats {0:ws_hi, 1:ws_lo, 2:wn_hi, 3:wn_lo};
// halfs index: (((m*4 + t)*8 + f)*64 + lane)*8 + j
// holds W[k = t*32 + (lane>>4)*8 + j][col = f*16 + (lane&15)]

#define WP_LAYER (4 * 4 * 8 * 64 * 8)  // 65536 halfs / layer
#define WP_MAT (4 * 8 * 64 * 8)        // 16384 halfs / matrix

__global__ void k_wpack(const float* __restrict__ ws0, const float* __restrict__ wn0,
                        const float* __restrict__ ws1, const float* __restrict__ wn1,
                        const float* __restrict__ ws2, const float* __restrict__ wn2,
                        const float* __restrict__ ws3, const float* __restrict__ wn3,
                        _Float16* __restrict__ wp) {
  int tid = blockIdx.x * 256 + threadIdx.x;  // 0..32767
  int l = tid & 63;
  int f = (tid >> 6) & 7;
  int t = (tid >> 9) & 3;
  int m = (tid >> 11) & 3;
  int layer = tid >> 13;
  const float* srcs[8] = {ws0, wn0, ws1, wn1, ws2, wn2, ws3, wn3};
  const float* src = srcs[layer * 2 + (m >> 1)];
  int isLo = m & 1;
  _Float16* dstp = wp + (size_t)layer * WP_LAYER + ((((m * 4 + t) * 8 + f) * 64 + l) * 8);
  int k0 = t * 32 + (l >> 4) * 8;
  int col = f * 16 + (l & 15);
#pragma unroll
  for (int j = 0; j < 8; ++j) {
    float v = src[(k0 + j) * DIM + col];
    _Float16 h1 = (_Float16)v;
    dstp[j] = isLo ? (_Float16)(v - (float)h1) : h1;
  }
}

// ---------------- aggregation: one wave per node, f16 gather, unroll 8 ----------------

__device__ __forceinline__ float f16lo(unsigned w) {
  union { unsigned u; _Float16 h[2]; } c;
  c.u = w;
  return (float)c.h[0];
}
__device__ __forceinline__ float f16hi(unsigned w) {
  union { unsigned u; _Float16 h[2]; } c;
  c.u = w;
  return (float)c.h[1];
}

__global__ void k_agg_f16(const _Float16* __restrict__ h1, const int* __restrict__ offs,
                          const int* __restrict__ esrc, const float* __restrict__ deg_inv,
                          _Float16* __restrict__ m1) {
  int wid = (blockIdx.x * blockDim.x + threadIdx.x) >> 6;  // node id
  int lane = threadIdx.x & 63;
  if (wid >= N_NODES) return;
  const unsigned* H = reinterpret_cast<const unsigned*>(h1);  // row = 64 u32
  int beg = offs[wid], end = offs[wid + 1];
  float xs[8] = {0.f, 0.f, 0.f, 0.f, 0.f, 0.f, 0.f, 0.f};
  float ys[8] = {0.f, 0.f, 0.f, 0.f, 0.f, 0.f, 0.f, 0.f};
  int e = beg;
  for (; e + 7 < end; e += 8) {
    int s[8];
#pragma unroll
    for (int j = 0; j < 8; ++j) s[j] = esrc[e + j];
    unsigned w[8];
#pragma unroll
    for (int j = 0; j < 8; ++j) w[j] = H[(size_t)s[j] * 64 + lane];
#pragma unroll
    for (int j = 0; j < 8; ++j) {
      xs[j] += f16lo(w[j]);
      ys[j] += f16hi(w[j]);
    }
  }
  for (; e + 1 < end; e += 2) {
    unsigned w0 = H[(size_t)esrc[e] * 64 + lane];
    unsigned w1 = H[(size_t)esrc[e + 1] * 64 + lane];
    xs[0] += f16lo(w0); ys[0] += f16hi(w0);
    xs[1] += f16lo(w1); ys[1] += f16hi(w1);
  }
  if (e < end) {
    unsigned w0 = H[(size_t)esrc[e] * 64 + lane];
    xs[2] += f16lo(w0); ys[2] += f16hi(w0);
  }
  float di = deg_inv[wid];
  float rx = ((xs[0] + xs[1]) + (xs[2] + xs[3])) + ((xs[4] + xs[5]) + (xs[6] + xs[7]));
  float ry = ((ys[0] + ys[1]) + (ys[2] + ys[3])) + ((ys[4] + ys[5]) + (ys[6] + ys[7]));
  rx *= di;
  ry *= di;
  union { unsigned u; _Float16 h[2]; } o;
  o.h[0] = (_Float16)rx;
  o.h[1] = (_Float16)ry;
  reinterpret_cast<unsigned*>(m1)[(size_t)wid * 64 + lane] = o.u;
}

// ---------------- MFMA dual-GEMM v3: LDS-staged, double-buffered ----------------
// out = act(h@ws + mean@wn + b); h = h1+h2 (f16 planes), mean = m1 (f16).
// acc += h1*ws1 + h2*ws1 + h1*ws2 + m1*wn1 + m1*wn2   (5 MFMAs per frag)
// Block = 256 threads = 4 waves (2x2); wave = 64 rows x 64 cols (4x4 frags).
// A planes staged to LDS via global_load_lds width-16, double-buffered (48 KB).
// LDS plane layout: [128 rows][32 halfs] linear (row = 64B): b128 frag reads hit
// the 8-lanes/bank-group floor for ds_read_b128 (conflict-free).
// B read direct from global (256KB frag-packed, L2-resident, lane-contiguous 16B).

template <int RELU, int LAST>
__global__ __launch_bounds__(256) void k_gemm_f16(
    const _Float16* __restrict__ hp1, const _Float16* __restrict__ hp2,
    const _Float16* __restrict__ mp1, const _Float16* __restrict__ wp,
    const float* __restrict__ bias, float* __restrict__ outf,
    _Float16* __restrict__ o1, _Float16* __restrict__ o2) {
  __shared__ _Float16 sA[2][3][128 * 32];  // [buf][plane][row*32 + k]  48 KB

  const int tid = threadIdx.x;
  const int lane = tid & 63;
  const int wv = tid >> 6;
  const int wr = wv >> 1;  // wave row group (0..1): rows wr*64..wr*64+63
  const int wc = wv & 1;   // wave col group (0..1): cols wc*64..wc*64+63
  const int row0 = blockIdx.x * 128;
  const int lr = lane & 15;  // row-in-frag (A) / col (B,C)
  const int lg = lane >> 4;  // k-group (A,B) / row-group (C)

  // staging decomposition: thread tid covers (row = j*64 + tid/4, kchunk = tid%4)
  const int srow = tid >> 2;
  const int skc = tid & 3;

  const _Float16* planes[3] = {hp1, hp2, mp1};

  f32x4 acc[4][4];  // [ri][fc]
#pragma unroll
  for (int i = 0; i < 4; ++i)
#pragma unroll
    for (int j = 0; j < 4; ++j) acc[i][j] = (f32x4){0.f, 0.f, 0.f, 0.f};

  const _Float16* WS1 = wp;               // ws hi
  const _Float16* WS2 = wp + WP_MAT;      // ws lo
  const _Float16* WN1 = wp + 2 * WP_MAT;  // wn hi
  const _Float16* WN2 = wp + 3 * WP_MAT;  // wn lo

  // ---- prologue: stage t=0 into buf 0 ----
#pragma unroll
  for (int p = 0; p < 3; ++p)
#pragma unroll
    for (int j = 0; j < 2; ++j) {
      const _Float16* g =
          planes[p] + (size_t)(row0 + j * 64 + srow) * DIM + 0 * 32 + skc * 8;
      _Float16* l = &sA[0][p][j * 2048 + (tid & ~63) * 8];
      stage16(g, l);
    }
  __syncthreads();

#pragma unroll
  for (int t = 0; t < 4; ++t) {
    const int cur = t & 1;
    // ---- stage next k-tile into the other buffer (async DMA) ----
    if (t < 3) {
      const int nxt = cur ^ 1;
#pragma unroll
      for (int p = 0; p < 3; ++p)
#pragma unroll
        for (int j = 0; j < 2; ++j) {
          const _Float16* g =
              planes[p] + (size_t)(row0 + j * 64 + srow) * DIM + (t + 1) * 32 + skc * 8;
          _Float16* l = &sA[nxt][p][j * 2048 + (tid & ~63) * 8];
          stage16(g, l);
        }
    }
    // ---- A frags from LDS ----
    f16x8 a1[4], a2[4], am[4];
#pragma unroll
    for (int ri = 0; ri < 4; ++ri) {
      int ro = (wr * 64 + ri * 16 + lr) * 32 + lg * 8;
      a1[ri] = *reinterpret_cast<const f16x8*>(&sA[cur][0][ro]);
      a2[ri] = *reinterpret_cast<const f16x8*>(&sA[cur][1][ro]);
      am[ri] = *reinterpret_cast<const f16x8*>(&sA[cur][2][ro]);
    }
    // ---- B frags from global (L2) + MFMA ----
#pragma unroll
    for (int fc = 0; fc < 4; ++fc) {
      int f = wc * 4 + fc;
      size_t boff = (size_t)((t * 8 + f) * 64 + lane) * 8;
      f16x8 bs1 = *reinterpret_cast<const f16x8*>(WS1 + boff);
      f16x8 bs2 = *reinterpret_cast<const f16x8*>(WS2 + boff);
      f16x8 bn1 = *reinterpret_cast<const f16x8*>(WN1 + boff);
      f16x8 bn2 = *reinterpret_cast<const f16x8*>(WN2 + boff);
#pragma unroll
      for (int ri = 0; ri < 4; ++ri) {
        acc[ri][fc] =
            __builtin_amdgcn_mfma_f32_16x16x32_f16(a1[ri], bs1, acc[ri][fc], 0, 0, 0);
        acc[ri][fc] =
            __builtin_amdgcn_mfma_f32_16x16x32_f16(a2[ri], bs1, acc[ri][fc], 0, 0, 0);
        acc[ri][fc] =
            __builtin_amdgcn_mfma_f32_16x16x32_f16(a1[ri], bs2, acc[ri][fc], 0, 0, 0);
        acc[ri][fc] =
            __builtin_amdgcn_mfma_f32_16x16x32_f16(am[ri], bn1, acc[ri][fc], 0, 0, 0);
        acc[ri][fc] =
            __builtin_amdgcn_mfma_f32_16x16x32_f16(am[ri], bn2, acc[ri][fc], 0, 0, 0);
      }
    }
    // drain DMA + protect buffer reuse (compiler emits vmcnt(0) lgkmcnt(0) here)
    __syncthreads();
  }

  // ---- epilogue: C/D layout col=lane&15, row=(lane>>4)*4+reg ----
  float bv[4];
#pragma unroll
  for (int fc = 0; fc < 4; ++fc) bv[fc] = bias[wc * 64 + fc * 16 + lr];
#pragma unroll
  for (int ri = 0; ri < 4; ++ri)
#pragma unroll
    for (int fc = 0; fc < 4; ++fc)
#pragma unroll
      for (int r = 0; r < 4; ++r) {
        int row = row0 + wr * 64 + ri * 16 + lg * 4 + r;
        if (row < N_NODES) {
          float v = acc[ri][fc][r] + bv[fc];
          if (RELU) v = fmaxf(v, 0.f);
          size_t idx = (size_t)row * DIM + wc * 64 + fc * 16 + lr;
          if (LAST) {
            outf[idx] = v;
          } else {
            _Float16 hi = (_Float16)v;
            o1[idx] = hi;
            o2[idx] = (_Float16)(v - (float)hi);
          }
        }
      }
}

// ---------------- driver ----------------

extern "C" void kernel_launch(void* const* d_in, const int* in_sizes, int n_in,
                              void* d_out, int out_size, void* d_ws, size_t ws_size,
                              hipStream_t stream) {
  const float* x = (const float*)d_in[0];
  const int* src = (const int*)d_in[1];
  const int* dst = (const int*)d_in[2];
  const float* Ws[4];
  const float* Wn[4];
  const float* Bi[4];
  for (int i = 0; i < 4; ++i) {
    Ws[i] = (const float*)d_in[3 + 3 * i];
    Wn[i] = (const float*)d_in[4 + 3 * i];
    Bi[i] = (const float*)d_in[5 + 3 * i];
  }
  float* out = (float*)d_out;

  char* p = (char*)d_ws;
  auto take = [&](size_t bytes) {
    void* r = (void*)p;
    p += (bytes + 255) & ~(size_t)255;
    return r;
  };
  int* cnt = (int*)take((size_t)N_NODES * 4);
  int* offs = (int*)take((size_t)(N_NODES + 1) * 4);
  int* cursor = (int*)take((size_t)N_NODES * 4);
  int* partials = (int*)take(128 * 4);
  float* deg_inv = (float*)take((size_t)N_NODES * 4);
  int* esrc = (int*)take((size_t)N_EDGES * 4);
  _Float16* hA1 = (_Float16*)take((size_t)N_NODES * DIM * 2);
  _Float16* hA2 = (_Float16*)take((size_t)N_NODES * DIM * 2);
  _Float16* hB1 = (_Float16*)take((size_t)N_NODES * DIM * 2);
  _Float16* hB2 = (_Float16*)take((size_t)N_NODES * DIM * 2);
  _Float16* m1 = (_Float16*)take((size_t)N_NODES * DIM * 2);
  _Float16* wpk = (_Float16*)take((size_t)4 * WP_LAYER * 2);
  // pad so last-block OOB staging reads stay inside the workspace
  (void)take((size_t)64 * 1024);

  const int NB = (N_NODES + 1023) / 1024;  // 98

  // CSR build (edges are layer-invariant)
  k_zero<<<(N_NODES + 255) / 256, 256, 0, stream>>>(cnt, N_NODES);
  k_count<<<(N_EDGES + 255) / 256, 256, 0, stream>>>(dst, cnt);
  k_scan_blk<<<NB, 1024, 0, stream>>>(cnt, offs, partials);
  k_scan_part<<<1, 128, 0, stream>>>(partials, NB);
  k_scan_add<<<(N_NODES + 255) / 256, 256, 0, stream>>>(offs, partials);
  k_prep<<<(N_NODES + 255) / 256, 256, 0, stream>>>(offs, cnt, cursor, deg_inv);
  k_fill8<<<8 * FILL_BPP, 256, 0, stream>>>(src, dst, cursor, esrc);

  // input conversion + weight pack
  k_xcvt<<<(N_NODES * DIM / 4 + 255) / 256, 256, 0, stream>>>(x, hA1, hA2);
  k_wpack<<<128, 256, 0, stream>>>(Ws[0], Wn[0], Ws[1], Wn[1], Ws[2], Wn[2], Ws[3], Wn[3],
                                   wpk);

  const int AGG_BLOCKS = (N_NODES + 3) / 4;       // 4 waves/block, 1 node/wave
  const int GEMM_BLOCKS = (N_NODES + 127) / 128;  // 128 rows x 128 cols per block

  _Float16 *h1 = hA1, *h2 = hA2, *n1 = hB1, *n2 = hB2;
  for (int l = 0; l < 4; ++l) {
    k_agg_f16<<<AGG_BLOCKS, 256, 0, stream>>>(h1, offs, esrc, deg_inv, m1);
    const _Float16* wl = wpk + (size_t)l * WP_LAYER;
    if (l < 3) {
      k_gemm_f16<1, 0><<<GEMM_BLOCKS, 256, 0, stream>>>(h1, h2, m1, wl, Bi[l], nullptr,
                                                        n1, n2);
      _Float16* t1 = h1; h1 = n1; n1 = t1;
      _Float16* t2 = h2; h2 = n2; n2 = t2;
    } else {
      k_gemm_f16<0, 1><<<GEMM_BLOCKS, 256, 0, stream>>>(h1, h2, m1, wl, Bi[l], out,
                                                        nullptr, nullptr);
    }
  }
}